// Round 1
// baseline (3689.879 us; speedup 1.0000x reference)
//
#include <hip/hip_runtime.h>

#define DEVINL __device__ __forceinline__

constexpr int N_NODES  = 20000;
constexpr int N_EDGES  = 320000;
constexpr int IN_FEATS = 512;

static_assert(N_EDGES % 64 == 0, "edge tiling assumes E % 64 == 0");
static_assert(N_NODES % 4 == 0, "proj assumes N % 4 == 0");

// ---- monotone float<->uint order encoding (for atomicMax-based segment_max) ----
// enc is strictly increasing with float value; memset-0 init decodes to NaN
// (treated as "empty segment" -> 0 by fixup, matching jnp.where(isfinite,...,0)).
DEVINL unsigned enc_f32(float v) {
  unsigned b = __float_as_uint(v);
  return (b & 0x80000000u) ? ~b : (b | 0x80000000u);
}
DEVINL float dec_f32(unsigned e) {
  unsigned b = (e & 0x80000000u) ? (e & 0x7FFFFFFFu) : ~e;
  return __uint_as_float(b);
}

// ---------------- small utility kernels ----------------
__global__ void fill_ones(float* p, int n) {
  int i = blockIdx.x * 256 + threadIdx.x;
  if (i < n) p[i] = 1.0f;
}
__global__ void count_deg(const int* __restrict__ dst, float* __restrict__ deg, int e) {
  int i = blockIdx.x * 256 + threadIdx.x;
  if (i < e) atomicAdd(&deg[dst[i]], 1.0f);
}
__global__ void fin_dinv(float* p, int n) {
  int i = blockIdx.x * 256 + threadIdx.x;
  if (i < n) p[i] = rsqrtf(p[i]);  // deg >= 1 always (self-loop)
}
__global__ void bn_prep(const float* __restrict__ g, const float* __restrict__ b,
                        const float* __restrict__ m, const float* __restrict__ v,
                        float* __restrict__ scale, float* __restrict__ shift, int n) {
  int i = blockIdx.x * 256 + threadIdx.x;
  if (i < n) {
    float s = g[i] * rsqrtf(v[i] + 1e-5f);
    scale[i] = s;
    shift[i] = b[i] - m[i] * s;
  }
}
// decode + isfinite->0, in place (u and f alias; elementwise i->i so safe)
__global__ void fixup_kernel(const unsigned* u, float* f, int n) {
  int i = blockIdx.x * 256 + threadIdx.x;
  if (i < n) {
    float v = dec_f32(u[i]);
    unsigned b = __float_as_uint(v);
    bool fin = ((b >> 23) & 0xFFu) != 0xFFu;
    f[i] = fin ? v : 0.f;
  }
}

// ---------------- input projection: rows 0 mod 4 use Wm/bm, else Wc/bc ----------------
__global__ void __launch_bounds__(256)
proj_kernel(const float* __restrict__ X, const float* __restrict__ Wm,
            const float* __restrict__ bm, const float* __restrict__ Wc,
            const float* __restrict__ bc, float* __restrict__ X0) {
  __shared__ float xs[4][IN_FEATS];
  int tid = threadIdx.x;
  int rowBase = blockIdx.x * 4;
  for (int idx = tid; idx < 4 * IN_FEATS; idx += 256) {
    int r = idx >> 9, k = idx & 511;
    xs[r][k] = X[(size_t)(rowBase + r) * IN_FEATS + k];
  }
  __syncthreads();
  int r = tid >> 6, j = tid & 63;  // r==0 <=> global row % 4 == 0 (wave-uniform)
  const float* W = (r == 0) ? Wm : Wc;
  float acc = 0.f;
#pragma unroll 8
  for (int k = 0; k < IN_FEATS; ++k) acc = fmaf(xs[r][k], W[k * 64 + j], acc);
  float b = (r == 0) ? bm[j] : bc[j];
  X0[(size_t)(rowBase + r) * 64 + j] = acc + b;
}

// ---------------- GCN dense part: H = X@W ; Ginit = bias + H*dinv^2 (self-loop) ----------------
template <int K, int F>
__global__ void __launch_bounds__(256)
gcn_gemm_kernel(const float* __restrict__ X, const float* __restrict__ W,
                const float* __restrict__ bias, const float* __restrict__ dinv,
                float* __restrict__ Hout, float* __restrict__ Ginit, int n) {
  __shared__ float Xs[64][K + 1];
  __shared__ float Ws[K][65];
  int tid = threadIdx.x;
  int rowBase = blockIdx.x * 64;
  int colBase = blockIdx.y * 64;
  for (int idx = tid; idx < 64 * K; idx += 256) {
    int r = idx / K, k = idx % K;
    int row = rowBase + r;
    Xs[r][k] = (row < n) ? X[(size_t)row * K + k] : 0.f;
  }
  for (int idx = tid; idx < K * 64; idx += 256) {
    int k = idx >> 6, c = idx & 63;
    Ws[k][c] = W[(size_t)k * F + colBase + c];
  }
  __syncthreads();
  int tx = tid & 15, ty = tid >> 4;
  float acc[4][4] = {};
  for (int k = 0; k < K; ++k) {
    float a[4], b[4];
#pragma unroll
    for (int r = 0; r < 4; ++r) a[r] = Xs[ty * 4 + r][k];
#pragma unroll
    for (int c = 0; c < 4; ++c) b[c] = Ws[k][tx * 4 + c];
#pragma unroll
    for (int r = 0; r < 4; ++r)
#pragma unroll
      for (int c = 0; c < 4; ++c) acc[r][c] = fmaf(a[r], b[c], acc[r][c]);
  }
#pragma unroll
  for (int r = 0; r < 4; ++r) {
    int row = rowBase + ty * 4 + r;
    if (row < n) {
      float di = dinv[row];
      float d2 = di * di;
#pragma unroll
      for (int c = 0; c < 4; ++c) {
        int col = colBase + tx * 4 + c;
        float v = acc[r][c];
        Hout[(size_t)row * F + col] = v;
        Ginit[(size_t)row * F + col] = fmaf(v, d2, bias[col]);
      }
    }
  }
}

// ---------------- GCN sparse part: G[dst] += H[src] * dinv[src]*dinv[dst] ----------------
template <int F>
__global__ void __launch_bounds__(256)
gcn_scatter_kernel(const float* __restrict__ Hin, const int* __restrict__ src,
                   const int* __restrict__ dst, const float* __restrict__ dinv,
                   float* __restrict__ G) {
  constexpr int EPB = 256 / F;
  int le = threadIdx.x / F;
  int j = threadIdx.x % F;
  int e = blockIdx.x * EPB + le;
  int s = src[e], d = dst[e];
  float c = dinv[s] * dinv[d];
  atomicAdd(&G[(size_t)d * F + j], Hin[(size_t)s * F + j] * c);
}

// ---------------- EdgeConv: feat=[x_d, x_s-x_d] -> BN -> ReLU -> @W[2C,128] -> max by dst ----
// 64 edges x 128 feats per block, K-chunks of 64, BN fused into A-stage.
template <int C>  // C = input feature width; BN dim = 2C; output F = 128
__global__ void __launch_bounds__(256)
edgeconv_kernel(const float* __restrict__ X, const int* __restrict__ src,
                const int* __restrict__ dst, const float* __restrict__ scale,
                const float* __restrict__ shift, const float* __restrict__ W,
                unsigned* __restrict__ outU) {
  constexpr int TWO_C = 2 * C;
  constexpr int AP = 68;  // padded A row stride (floats), mult of 4 for float4 stores
  __shared__ float As[64 * AP];
  __shared__ float Bs[64 * 128];
  __shared__ int se[64], de[64];
  int tid = threadIdx.x;
  int ebase = blockIdx.x * 64;
  if (tid < 64) {
    se[tid] = src[ebase + tid];
    de[tid] = dst[ebase + tid];
  }
  __syncthreads();
  int tx = tid & 15, ty = tid >> 4;
  float acc[4][8];
#pragma unroll
  for (int r = 0; r < 4; ++r)
#pragma unroll
    for (int c = 0; c < 8; ++c) acc[r][c] = 0.f;

  for (int kc = 0; kc < TWO_C; kc += 64) {
    // stage A: 64 edges x 64 k as float4 (BN+ReLU fused); chunk lies wholly in one half
#pragma unroll
    for (int i = 0; i < 4; ++i) {
      int idx = i * 256 + tid;
      int e = idx >> 4, q = idx & 15;
      int kg = kc + q * 4;
      float4 v;
      if (kc < C) {
        v = *reinterpret_cast<const float4*>(X + (size_t)de[e] * C + kg);
      } else {
        int k2 = kg - C;
        float4 a = *reinterpret_cast<const float4*>(X + (size_t)se[e] * C + k2);
        float4 b = *reinterpret_cast<const float4*>(X + (size_t)de[e] * C + k2);
        v = make_float4(a.x - b.x, a.y - b.y, a.z - b.z, a.w - b.w);
      }
      float4 sc = *reinterpret_cast<const float4*>(scale + kg);
      float4 sh = *reinterpret_cast<const float4*>(shift + kg);
      v.x = fmaxf(fmaf(v.x, sc.x, sh.x), 0.f);
      v.y = fmaxf(fmaf(v.y, sc.y, sh.y), 0.f);
      v.z = fmaxf(fmaf(v.z, sc.z, sh.z), 0.f);
      v.w = fmaxf(fmaf(v.w, sc.w, sh.w), 0.f);
      *reinterpret_cast<float4*>(&As[e * AP + q * 4]) = v;
    }
    // stage B: W chunk [64 x 128]
#pragma unroll
    for (int i = 0; i < 8; ++i) {
      int q = i * 256 + tid;
      int k = q >> 5, fq = q & 31;
      *reinterpret_cast<float4*>(&Bs[k * 128 + fq * 4]) =
          *reinterpret_cast<const float4*>(W + (size_t)(kc + k) * 128 + fq * 4);
    }
    __syncthreads();
    for (int kk = 0; kk < 64; ++kk) {
      float av[4];
#pragma unroll
      for (int r = 0; r < 4; ++r) av[r] = As[(ty * 4 + r) * AP + kk];
      float4 b0 = *reinterpret_cast<const float4*>(&Bs[kk * 128 + tx * 8]);
      float4 b1 = *reinterpret_cast<const float4*>(&Bs[kk * 128 + tx * 8 + 4]);
      float bv[8] = {b0.x, b0.y, b0.z, b0.w, b1.x, b1.y, b1.z, b1.w};
#pragma unroll
      for (int r = 0; r < 4; ++r)
#pragma unroll
        for (int c = 0; c < 8; ++c) acc[r][c] = fmaf(av[r], bv[c], acc[r][c]);
    }
    __syncthreads();
  }
  // epilogue: order-encoded atomic max into out[dst]
#pragma unroll
  for (int r = 0; r < 4; ++r) {
    int le = ty * 4 + r;
    unsigned* rowp = outU + (size_t)de[le] * 128 + tx * 8;
#pragma unroll
    for (int c = 0; c < 8; ++c) atomicMax(rowp + c, enc_f32(acc[r][c]));
  }
}

// ---------------- final FC: out[i] = h[i,0:128] . Wfc + bfc ----------------
__global__ void __launch_bounds__(256)
fc_kernel(const float* __restrict__ Hf, const float* __restrict__ Wfc,
          const float* __restrict__ bfc, float* __restrict__ out, int n) {
  int g = blockIdx.x * 256 + threadIdx.x;
  int node = g >> 6, lane = g & 63;
  if (node >= n) return;
  float v = fmaf(Hf[(size_t)node * 128 + lane], Wfc[lane],
                 Hf[(size_t)node * 128 + 64 + lane] * Wfc[64 + lane]);
#pragma unroll
  for (int off = 32; off > 0; off >>= 1) v += __shfl_down(v, off);
  if (lane == 0) out[node] = v + bfc[0];
}

extern "C" void kernel_launch(void* const* d_in, const int* in_sizes, int n_in,
                              void* d_out, int out_size, void* d_ws, size_t ws_size,
                              hipStream_t stream) {
  const float* x   = (const float*)d_in[0];
  const int*   ei  = (const int*)d_in[1];
  const float* Wm  = (const float*)d_in[2];
  const float* bm  = (const float*)d_in[3];
  const float* Wc  = (const float*)d_in[4];
  const float* bc  = (const float*)d_in[5];
  const float* Wg1 = (const float*)d_in[6];
  const float* bg1 = (const float*)d_in[7];
  const float* Wg2 = (const float*)d_in[8];
  const float* bg2 = (const float*)d_in[9];
  const float* Wg3 = (const float*)d_in[10];
  const float* bg3 = (const float*)d_in[11];
  const float* e1g = (const float*)d_in[12];
  const float* e1b = (const float*)d_in[13];
  const float* e1m = (const float*)d_in[14];
  const float* e1v = (const float*)d_in[15];
  const float* e1W = (const float*)d_in[16];
  const float* e2g = (const float*)d_in[17];
  const float* e2b = (const float*)d_in[18];
  const float* e2m = (const float*)d_in[19];
  const float* e2v = (const float*)d_in[20];
  const float* e2W = (const float*)d_in[21];
  const float* e3g = (const float*)d_in[22];
  const float* e3b = (const float*)d_in[23];
  const float* e3m = (const float*)d_in[24];
  const float* e3v = (const float*)d_in[25];
  const float* e3W = (const float*)d_in[26];
  const float* Wfc = (const float*)d_in[27];
  const float* bfc = (const float*)d_in[28];

  const int* src = ei;            // edge_index[0]
  const int* dst = ei + N_EDGES;  // edge_index[1]

  // workspace layout (floats): ~66.7 MB total
  float* ws   = (float*)d_ws;
  float* dinv = ws;                                  // N
  float* x0   = dinv + N_NODES;                      // N*64
  float* hbuf = x0 + (size_t)N_NODES * 64;           // N*256
  float* gA   = hbuf + (size_t)N_NODES * 256;        // N*256
  float* gB   = gA + (size_t)N_NODES * 256;          // N*256
  float* sc1  = gB + (size_t)N_NODES * 256;          // 512
  float* sh1  = sc1 + 512;                           // 512
  float* sc2  = sh1 + 512;                           // 256
  float* sh2  = sc2 + 256;                           // 256
  float* sc3  = sh2 + 256;                           // 256
  float* sh3  = sc3 + 256;                           // 256

  // degree (with self-loop) -> dinv
  fill_ones<<<79, 256, 0, stream>>>(dinv, N_NODES);
  count_deg<<<N_EDGES / 256, 256, 0, stream>>>(dst, dinv, N_EDGES);
  fin_dinv<<<79, 256, 0, stream>>>(dinv, N_NODES);

  // BN folded scale/shift
  bn_prep<<<2, 256, 0, stream>>>(e1g, e1b, e1m, e1v, sc1, sh1, 512);
  bn_prep<<<1, 256, 0, stream>>>(e2g, e2b, e2m, e2v, sc2, sh2, 256);
  bn_prep<<<1, 256, 0, stream>>>(e3g, e3b, e3m, e3v, sc3, sh3, 256);

  // x0 projection (row%4 selects Wm vs Wc)
  proj_kernel<<<N_NODES / 4, 256, 0, stream>>>(x, Wm, bm, Wc, bc, x0);

  // GCN layers: gemm (+bias+self-loop init) then edge scatter-add
  dim3 grid2(313, 2), grid4(313, 4);
  gcn_gemm_kernel<64, 128><<<grid2, 256, 0, stream>>>(x0, Wg1, bg1, dinv, hbuf, gA, N_NODES);
  gcn_scatter_kernel<128><<<N_EDGES / 2, 256, 0, stream>>>(hbuf, src, dst, dinv, gA);
  gcn_gemm_kernel<128, 128><<<grid2, 256, 0, stream>>>(gA, Wg2, bg2, dinv, hbuf, gB, N_NODES);
  gcn_scatter_kernel<128><<<N_EDGES / 2, 256, 0, stream>>>(hbuf, src, dst, dinv, gB);
  gcn_gemm_kernel<128, 256><<<grid4, 256, 0, stream>>>(gB, Wg3, bg3, dinv, hbuf, gA, N_NODES);
  gcn_scatter_kernel<256><<<N_EDGES, 256, 0, stream>>>(hbuf, src, dst, dinv, gA);

  // EdgeConv 1: input gA [N,256] -> gB [N,128]
  hipMemsetAsync(gB, 0, (size_t)N_NODES * 128 * 4, stream);
  edgeconv_kernel<256><<<N_EDGES / 64, 256, 0, stream>>>(gA, src, dst, sc1, sh1, e1W,
                                                         (unsigned*)gB);
  fixup_kernel<<<N_NODES * 128 / 256, 256, 0, stream>>>((const unsigned*)gB, gB, N_NODES * 128);

  // EdgeConv 2: input gB [N,128] -> gA [N,128]
  hipMemsetAsync(gA, 0, (size_t)N_NODES * 128 * 4, stream);
  edgeconv_kernel<128><<<N_EDGES / 64, 256, 0, stream>>>(gB, src, dst, sc2, sh2, e2W,
                                                         (unsigned*)gA);
  fixup_kernel<<<N_NODES * 128 / 256, 256, 0, stream>>>((const unsigned*)gA, gA, N_NODES * 128);

  // EdgeConv 3: input gA [N,128] -> hbuf [N,128]
  hipMemsetAsync(hbuf, 0, (size_t)N_NODES * 128 * 4, stream);
  edgeconv_kernel<128><<<N_EDGES / 64, 256, 0, stream>>>(gA, src, dst, sc3, sh3, e3W,
                                                         (unsigned*)hbuf);
  fixup_kernel<<<N_NODES * 128 / 256, 256, 0, stream>>>((const unsigned*)hbuf, hbuf,
                                                        N_NODES * 128);

  // final FC
  fc_kernel<<<N_NODES * 64 / 256, 256, 0, stream>>>(hbuf, Wfc, bfc, (float*)d_out, N_NODES);
}

// Round 2
// 2399.316 us; speedup vs baseline: 1.5379x; 1.5379x over previous
//
#include <hip/hip_runtime.h>

#define DEVINL __device__ __forceinline__

constexpr int N_NODES  = 20000;
constexpr int N_EDGES  = 320000;
constexpr int IN_FEATS = 512;

static_assert(N_EDGES % 128 == 0, "edge tiling assumes E % 128 == 0");
static_assert(N_NODES % 4 == 0, "proj assumes N % 4 == 0");

// ---- monotone float<->uint order encoding (for atomicMax-based segment_max) ----
// enc is strictly increasing with float value; enc(finite) != 0, so memset-0
// init marks "empty segment" (reference: -inf -> 0 via isfinite fixup).
DEVINL unsigned enc_f32(float v) {
  unsigned b = __float_as_uint(v);
  return (b & 0x80000000u) ? ~b : (b | 0x80000000u);
}
DEVINL float dec_f32(unsigned e) {
  unsigned b = (e & 0x80000000u) ? (e & 0x7FFFFFFFu) : ~e;
  return __uint_as_float(b);
}

// ---------------- small utility kernels ----------------
__global__ void fill_ones(float* p, int n) {
  int i = blockIdx.x * 256 + threadIdx.x;
  if (i < n) p[i] = 1.0f;
}
__global__ void count_deg(const int* __restrict__ dst, float* __restrict__ deg, int e) {
  int i = blockIdx.x * 256 + threadIdx.x;
  if (i < e) atomicAdd(&deg[dst[i]], 1.0f);
}
__global__ void fin_dinv(float* p, int n) {
  int i = blockIdx.x * 256 + threadIdx.x;
  if (i < n) p[i] = rsqrtf(p[i]);  // deg >= 1 always (self-loop)
}
__global__ void bn_prep(const float* __restrict__ g, const float* __restrict__ b,
                        const float* __restrict__ m, const float* __restrict__ v,
                        float* __restrict__ scale, float* __restrict__ shift, int n) {
  int i = blockIdx.x * 256 + threadIdx.x;
  if (i < n) {
    float s = g[i] * rsqrtf(v[i] + 1e-5f);
    scale[i] = s;
    shift[i] = b[i] - m[i] * s;
  }
}
// out = (Q written) ? P + dec(Q) : 0   (empty segment -> 0, matches reference)
__global__ void combine_kernel(const unsigned* __restrict__ Q, const float* __restrict__ P,
                               float* __restrict__ H, int n) {
  int i = blockIdx.x * 256 + threadIdx.x;
  if (i < n) {
    unsigned e = Q[i];
    H[i] = e ? (P[i] + dec_f32(e)) : 0.f;
  }
}

// ---------------- input projection: rows 0 mod 4 use Wm/bm, else Wc/bc ----------------
__global__ void __launch_bounds__(256)
proj_kernel(const float* __restrict__ X, const float* __restrict__ Wm,
            const float* __restrict__ bm, const float* __restrict__ Wc,
            const float* __restrict__ bc, float* __restrict__ X0) {
  __shared__ float xs[4][IN_FEATS];
  int tid = threadIdx.x;
  int rowBase = blockIdx.x * 4;
  for (int idx = tid; idx < 4 * IN_FEATS; idx += 256) {
    int r = idx >> 9, k = idx & 511;
    xs[r][k] = X[(size_t)(rowBase + r) * IN_FEATS + k];
  }
  __syncthreads();
  int r = tid >> 6, j = tid & 63;  // r==0 <=> global row % 4 == 0 (wave-uniform)
  const float* W = (r == 0) ? Wm : Wc;
  float acc = 0.f;
#pragma unroll 8
  for (int k = 0; k < IN_FEATS; ++k) acc = fmaf(xs[r][k], W[k * 64 + j], acc);
  float b = (r == 0) ? bm[j] : bc[j];
  X0[(size_t)(rowBase + r) * 64 + j] = acc + b;
}

// ---------------- GCN dense part: H = X@W ; Ginit = bias + H*dinv^2 (self-loop) ----------------
template <int K, int F>
__global__ void __launch_bounds__(256)
gcn_gemm_kernel(const float* __restrict__ X, const float* __restrict__ W,
                const float* __restrict__ bias, const float* __restrict__ dinv,
                float* __restrict__ Hout, float* __restrict__ Ginit, int n) {
  __shared__ float Xs[64][K + 1];
  __shared__ float Ws[K][65];
  int tid = threadIdx.x;
  int rowBase = blockIdx.x * 64;
  int colBase = blockIdx.y * 64;
  for (int idx = tid; idx < 64 * K; idx += 256) {
    int r = idx / K, k = idx % K;
    int row = rowBase + r;
    Xs[r][k] = (row < n) ? X[(size_t)row * K + k] : 0.f;
  }
  for (int idx = tid; idx < K * 64; idx += 256) {
    int k = idx >> 6, c = idx & 63;
    Ws[k][c] = W[(size_t)k * F + colBase + c];
  }
  __syncthreads();
  int tx = tid & 15, ty = tid >> 4;
  float acc[4][4] = {};
  for (int k = 0; k < K; ++k) {
    float a[4], b[4];
#pragma unroll
    for (int r = 0; r < 4; ++r) a[r] = Xs[ty * 4 + r][k];
#pragma unroll
    for (int c = 0; c < 4; ++c) b[c] = Ws[k][tx * 4 + c];
#pragma unroll
    for (int r = 0; r < 4; ++r)
#pragma unroll
      for (int c = 0; c < 4; ++c) acc[r][c] = fmaf(a[r], b[c], acc[r][c]);
  }
#pragma unroll
  for (int r = 0; r < 4; ++r) {
    int row = rowBase + ty * 4 + r;
    if (row < n) {
      float di = dinv[row];
      float d2 = di * di;
#pragma unroll
      for (int c = 0; c < 4; ++c) {
        int col = colBase + tx * 4 + c;
        float v = acc[r][c];
        Hout[(size_t)row * F + col] = v;
        Ginit[(size_t)row * F + col] = fmaf(v, d2, bias[col]);
      }
    }
  }
}

// ---------------- GCN sparse part: G[dst] += H[src] * dinv[src]*dinv[dst] ----------------
template <int F>
__global__ void __launch_bounds__(256)
gcn_scatter_kernel(const float* __restrict__ Hin, const int* __restrict__ src,
                   const int* __restrict__ dst, const float* __restrict__ dinv,
                   float* __restrict__ G) {
  constexpr int EPB = 256 / F;
  int le = threadIdx.x / F;
  int j = threadIdx.x % F;
  int e = blockIdx.x * EPB + le;
  int s = src[e], d = dst[e];
  float c = dinv[s] * dinv[d];
  atomicAdd(&G[(size_t)d * F + j], Hin[(size_t)s * F + j] * c);
}

// ---------------- EdgeConv split GEMM ----------------
// EdgeConv(feat=[x_d, x_s-x_d]) with elementwise BN+ReLU splits as
//   h_e = ReLU(BN_top(x_d))@W_top + ReLU(BN_bot(x_s-x_d))@W_bot
// and segment_max_d(h) = P[d] + segment_max_d(Q_e), P per-node, Q per-edge.
//
// This kernel computes either P (EDGE=false: rows = nodes, plain store) or
// Q (EDGE=true: rows = edges, order-encoded atomicMax into outU[dst]).
// Tile: 128 rows x 128 cols, 256 threads, 8x8 per-thread, K-chunk 32.
// LDS layouts XOR-swizzled so all inner-loop reads are b128 with <=2-way
// bank aliasing (free per m136); LDS bytes/FLOP = 0.5 (balanced vs 128B/cyc).
template <int C, bool EDGE>
__global__ void __launch_bounds__(256, 3)
ec_gemm_kernel(const float* __restrict__ X, const int* __restrict__ src,
               const int* __restrict__ dst, const float* __restrict__ scale,
               const float* __restrict__ shift, const float* __restrict__ W,
               unsigned* __restrict__ outU, float* __restrict__ outP, int nrows) {
  __shared__ float As[128 * 32];  // row-major, col-group XOR-swizzled by (row>>3)&7
  __shared__ float Bs[32 * 128];  // row-major, col-group XOR-swizzled by kk&7
  __shared__ int se[128], de[128];
  const int tid = threadIdx.x;
  const int base = blockIdx.x * 128;
  if (EDGE && tid < 128) {
    se[tid] = src[base + tid];
    de[tid] = dst[base + tid];
  }
  __syncthreads();

  const int tx = tid & 15, ty = tid >> 4;
  const int sA = ty & 7;
  float acc[8][8] = {};

  for (int kc = 0; kc < C; kc += 32) {
    // ---- stage A: 128 rows x 32 k, BN+ReLU fused, float4 tasks ----
#pragma unroll
    for (int i = 0; i < 4; ++i) {
      int idx = i * 256 + tid;
      int e = idx >> 3, cg = idx & 7;  // row, 4-float col-group
      int kg = kc + cg * 4;
      float4 v;
      if (EDGE) {
        float4 a = *reinterpret_cast<const float4*>(X + (size_t)se[e] * C + kg);
        float4 b = *reinterpret_cast<const float4*>(X + (size_t)de[e] * C + kg);
        v = make_float4(a.x - b.x, a.y - b.y, a.z - b.z, a.w - b.w);
      } else {
        int row = base + e;
        if (row >= nrows) row = nrows - 1;  // clamp; epilogue guards stores
        v = *reinterpret_cast<const float4*>(X + (size_t)row * C + kg);
      }
      float4 sc = *reinterpret_cast<const float4*>(scale + kg);
      float4 sh = *reinterpret_cast<const float4*>(shift + kg);
      v.x = fmaxf(fmaf(v.x, sc.x, sh.x), 0.f);
      v.y = fmaxf(fmaf(v.y, sc.y, sh.y), 0.f);
      v.z = fmaxf(fmaf(v.z, sc.z, sh.z), 0.f);
      v.w = fmaxf(fmaf(v.w, sc.w, sh.w), 0.f);
      *reinterpret_cast<float4*>(&As[e * 32 + ((cg ^ ((e >> 3) & 7)) << 2)]) = v;
    }
    // ---- stage B: 32 k x 128 cols ----
#pragma unroll
    for (int i = 0; i < 4; ++i) {
      int idx = i * 256 + tid;
      int kk = idx >> 5, cg = idx & 31;
      *reinterpret_cast<float4*>(&Bs[kk * 128 + ((cg ^ (kk & 7)) << 2)]) =
          *reinterpret_cast<const float4*>(W + (size_t)(kc + kk) * 128 + cg * 4);
    }
    __syncthreads();
    // ---- compute: 8x8 per thread, all-b128 LDS reads ----
#pragma unroll
    for (int kk4 = 0; kk4 < 8; ++kk4) {
      float4 a[8];
#pragma unroll
      for (int r = 0; r < 8; ++r)
        a[r] = *reinterpret_cast<const float4*>(
            &As[(ty * 8 + r) * 32 + ((kk4 ^ sA) << 2)]);
#pragma unroll
      for (int w = 0; w < 4; ++w) {
        int kk = kk4 * 4 + w;
        int k7 = kk & 7;
        float4 b0 = *reinterpret_cast<const float4*>(
            &Bs[kk * 128 + ((tx ^ k7) << 2)]);  // cols tx*4..+3
        float4 b1 = *reinterpret_cast<const float4*>(
            &Bs[kk * 128 + (((tx + 16) ^ k7) << 2)]);  // cols 64+tx*4..+3
#pragma unroll
        for (int r = 0; r < 8; ++r) {
          float av = reinterpret_cast<const float*>(&a[r])[w];
          acc[r][0] = fmaf(av, b0.x, acc[r][0]);
          acc[r][1] = fmaf(av, b0.y, acc[r][1]);
          acc[r][2] = fmaf(av, b0.z, acc[r][2]);
          acc[r][3] = fmaf(av, b0.w, acc[r][3]);
          acc[r][4] = fmaf(av, b1.x, acc[r][4]);
          acc[r][5] = fmaf(av, b1.y, acc[r][5]);
          acc[r][6] = fmaf(av, b1.z, acc[r][6]);
          acc[r][7] = fmaf(av, b1.w, acc[r][7]);
        }
      }
    }
    __syncthreads();
  }

  // ---- epilogue ----
  if (EDGE) {
#pragma unroll
    for (int r = 0; r < 8; ++r) {
      int d = de[ty * 8 + r];
      unsigned* p = outU + (size_t)d * 128 + tx * 4;
#pragma unroll
      for (int c = 0; c < 4; ++c) atomicMax(p + c, enc_f32(acc[r][c]));
#pragma unroll
      for (int c = 0; c < 4; ++c) atomicMax(p + 64 + c, enc_f32(acc[r][4 + c]));
    }
  } else {
#pragma unroll
    for (int r = 0; r < 8; ++r) {
      int row = base + ty * 8 + r;
      if (row < nrows) {
        *reinterpret_cast<float4*>(outP + (size_t)row * 128 + tx * 4) =
            make_float4(acc[r][0], acc[r][1], acc[r][2], acc[r][3]);
        *reinterpret_cast<float4*>(outP + (size_t)row * 128 + 64 + tx * 4) =
            make_float4(acc[r][4], acc[r][5], acc[r][6], acc[r][7]);
      }
    }
  }
}

// ---------------- final FC: out[i] = h[i,0:128] . Wfc + bfc ----------------
__global__ void __launch_bounds__(256)
fc_kernel(const float* __restrict__ Hf, const float* __restrict__ Wfc,
          const float* __restrict__ bfc, float* __restrict__ out, int n) {
  int g = blockIdx.x * 256 + threadIdx.x;
  int node = g >> 6, lane = g & 63;
  if (node >= n) return;
  float v = fmaf(Hf[(size_t)node * 128 + lane], Wfc[lane],
                 Hf[(size_t)node * 128 + 64 + lane] * Wfc[64 + lane]);
#pragma unroll
  for (int off = 32; off > 0; off >>= 1) v += __shfl_down(v, off);
  if (lane == 0) out[node] = v + bfc[0];
}

extern "C" void kernel_launch(void* const* d_in, const int* in_sizes, int n_in,
                              void* d_out, int out_size, void* d_ws, size_t ws_size,
                              hipStream_t stream) {
  const float* x   = (const float*)d_in[0];
  const int*   ei  = (const int*)d_in[1];
  const float* Wm  = (const float*)d_in[2];
  const float* bm  = (const float*)d_in[3];
  const float* Wc  = (const float*)d_in[4];
  const float* bc  = (const float*)d_in[5];
  const float* Wg1 = (const float*)d_in[6];
  const float* bg1 = (const float*)d_in[7];
  const float* Wg2 = (const float*)d_in[8];
  const float* bg2 = (const float*)d_in[9];
  const float* Wg3 = (const float*)d_in[10];
  const float* bg3 = (const float*)d_in[11];
  const float* e1g = (const float*)d_in[12];
  const float* e1b = (const float*)d_in[13];
  const float* e1m = (const float*)d_in[14];
  const float* e1v = (const float*)d_in[15];
  const float* e1W = (const float*)d_in[16];
  const float* e2g = (const float*)d_in[17];
  const float* e2b = (const float*)d_in[18];
  const float* e2m = (const float*)d_in[19];
  const float* e2v = (const float*)d_in[20];
  const float* e2W = (const float*)d_in[21];
  const float* e3g = (const float*)d_in[22];
  const float* e3b = (const float*)d_in[23];
  const float* e3m = (const float*)d_in[24];
  const float* e3v = (const float*)d_in[25];
  const float* e3W = (const float*)d_in[26];
  const float* Wfc = (const float*)d_in[27];
  const float* bfc = (const float*)d_in[28];

  const int* src = ei;            // edge_index[0]
  const int* dst = ei + N_EDGES;  // edge_index[1]

  // workspace layout (floats): same footprint as round 1 (~67 MB)
  float* ws   = (float*)d_ws;
  float* dinv = ws;                                  // N
  float* x0   = dinv + N_NODES;                      // N*64
  float* hbuf = x0 + (size_t)N_NODES * 64;           // N*256 (GCN H, then P|Q)
  float* gA   = hbuf + (size_t)N_NODES * 256;        // N*256
  float* gB   = gA + (size_t)N_NODES * 256;          // N*256
  float* sc1  = gB + (size_t)N_NODES * 256;          // 512
  float* sh1  = sc1 + 512;                           // 512
  float* sc2  = sh1 + 512;                           // 256
  float* sh2  = sc2 + 256;                           // 256
  float* sc3  = sh2 + 256;                           // 256
  float* sh3  = sc3 + 256;                           // 256

  float*    Pbuf = hbuf;                             // N*128 (after GCN, hbuf is free)
  unsigned* Qbuf = (unsigned*)(hbuf + (size_t)N_NODES * 128);  // N*128

  // degree (with self-loop) -> dinv
  fill_ones<<<79, 256, 0, stream>>>(dinv, N_NODES);
  count_deg<<<N_EDGES / 256, 256, 0, stream>>>(dst, dinv, N_EDGES);
  fin_dinv<<<79, 256, 0, stream>>>(dinv, N_NODES);

  // BN folded scale/shift
  bn_prep<<<2, 256, 0, stream>>>(e1g, e1b, e1m, e1v, sc1, sh1, 512);
  bn_prep<<<1, 256, 0, stream>>>(e2g, e2b, e2m, e2v, sc2, sh2, 256);
  bn_prep<<<1, 256, 0, stream>>>(e3g, e3b, e3m, e3v, sc3, sh3, 256);

  // x0 projection (row%4 selects Wm vs Wc)
  proj_kernel<<<N_NODES / 4, 256, 0, stream>>>(x, Wm, bm, Wc, bc, x0);

  // GCN layers: gemm (+bias+self-loop init) then edge scatter-add
  dim3 grid2(313, 2), grid4(313, 4);
  gcn_gemm_kernel<64, 128><<<grid2, 256, 0, stream>>>(x0, Wg1, bg1, dinv, hbuf, gA, N_NODES);
  gcn_scatter_kernel<128><<<N_EDGES / 2, 256, 0, stream>>>(hbuf, src, dst, dinv, gA);
  gcn_gemm_kernel<128, 128><<<grid2, 256, 0, stream>>>(gA, Wg2, bg2, dinv, hbuf, gB, N_NODES);
  gcn_scatter_kernel<128><<<N_EDGES / 2, 256, 0, stream>>>(hbuf, src, dst, dinv, gB);
  gcn_gemm_kernel<128, 256><<<grid4, 256, 0, stream>>>(gB, Wg3, bg3, dinv, hbuf, gA, N_NODES);
  gcn_scatter_kernel<256><<<N_EDGES, 256, 0, stream>>>(hbuf, src, dst, dinv, gA);

  const int NODE_BLOCKS = (N_NODES + 127) / 128;  // 157
  const int EDGE_BLOCKS = N_EDGES / 128;          // 2500
  const int NB_ELEM     = N_NODES * 128 / 256;    // 10000

  // EdgeConv 1: input gA [N,256] -> gB [N,128]
  hipMemsetAsync(Qbuf, 0, (size_t)N_NODES * 128 * 4, stream);
  ec_gemm_kernel<256, false><<<NODE_BLOCKS, 256, 0, stream>>>(
      gA, nullptr, nullptr, sc1, sh1, e1W, nullptr, Pbuf, N_NODES);
  ec_gemm_kernel<256, true><<<EDGE_BLOCKS, 256, 0, stream>>>(
      gA, src, dst, sc1 + 256, sh1 + 256, e1W + 256 * 128, Qbuf, nullptr, N_NODES);
  combine_kernel<<<NB_ELEM, 256, 0, stream>>>(Qbuf, Pbuf, gB, N_NODES * 128);

  // EdgeConv 2: input gB [N,128] -> gA [N,128]
  hipMemsetAsync(Qbuf, 0, (size_t)N_NODES * 128 * 4, stream);
  ec_gemm_kernel<128, false><<<NODE_BLOCKS, 256, 0, stream>>>(
      gB, nullptr, nullptr, sc2, sh2, e2W, nullptr, Pbuf, N_NODES);
  ec_gemm_kernel<128, true><<<EDGE_BLOCKS, 256, 0, stream>>>(
      gB, src, dst, sc2 + 128, sh2 + 128, e2W + 128 * 128, Qbuf, nullptr, N_NODES);
  combine_kernel<<<NB_ELEM, 256, 0, stream>>>(Qbuf, Pbuf, gA, N_NODES * 128);

  // EdgeConv 3: input gA [N,128] -> gB [N,128]
  hipMemsetAsync(Qbuf, 0, (size_t)N_NODES * 128 * 4, stream);
  ec_gemm_kernel<128, false><<<NODE_BLOCKS, 256, 0, stream>>>(
      gA, nullptr, nullptr, sc3, sh3, e3W, nullptr, Pbuf, N_NODES);
  ec_gemm_kernel<128, true><<<EDGE_BLOCKS, 256, 0, stream>>>(
      gA, src, dst, sc3 + 128, sh3 + 128, e3W + 128 * 128, Qbuf, nullptr, N_NODES);
  combine_kernel<<<NB_ELEM, 256, 0, stream>>>(Qbuf, Pbuf, gB, N_NODES * 128);

  // final FC
  fc_kernel<<<N_NODES * 64 / 256, 256, 0, stream>>>(gB, Wfc, bfc, (float*)d_out, N_NODES);
}

// Round 3
// 1267.243 us; speedup vs baseline: 2.9117x; 1.8933x over previous
//
#include <hip/hip_runtime.h>

#define DEVINL __device__ __forceinline__

constexpr int N_NODES  = 20000;
constexpr int N_EDGES  = 320000;
constexpr int IN_FEATS = 512;

static_assert(N_EDGES % 128 == 0, "edge tiling assumes E % 128 == 0");
static_assert(N_NODES % 4 == 0, "proj assumes N % 4 == 0");

// ---- monotone float<->uint order encoding (for atomicMax-based segment_max) ----
// enc is strictly increasing with float value; enc(finite) != 0, so memset-0
// init marks "empty segment" (reference: -inf -> 0 via isfinite fixup).
DEVINL unsigned enc_f32(float v) {
  unsigned b = __float_as_uint(v);
  return (b & 0x80000000u) ? ~b : (b | 0x80000000u);
}
DEVINL float dec_f32(unsigned e) {
  unsigned b = (e & 0x80000000u) ? (e & 0x7FFFFFFFu) : ~e;
  return __uint_as_float(b);
}

// ---------------- CSR build (counting sort by dst) ----------------
__global__ void hist_kernel(const int* __restrict__ dst, int* __restrict__ cnt, int e) {
  int i = blockIdx.x * 256 + threadIdx.x;
  if (i < e) atomicAdd(&cnt[dst[i]], 1);
}
__global__ void dinv_kernel(const int* __restrict__ cnt, float* __restrict__ dinv, int n) {
  int i = blockIdx.x * 256 + threadIdx.x;
  if (i < n) dinv[i] = rsqrtf((float)cnt[i] + 1.0f);  // +1 self-loop
}
// single-block exclusive scan over n counters -> row_ptr (and cursor copy)
__global__ void __launch_bounds__(256)
scan_kernel(const int* __restrict__ cnt, int* __restrict__ row_ptr,
            int* __restrict__ cursor, int n) {
  __shared__ int buf[256];
  __shared__ int carry;
  if (threadIdx.x == 0) carry = 0;
  __syncthreads();
  for (int base = 0; base < n; base += 256) {
    int i = base + threadIdx.x;
    int v = (i < n) ? cnt[i] : 0;
    buf[threadIdx.x] = v;
    __syncthreads();
    for (int off = 1; off < 256; off <<= 1) {
      int t = (threadIdx.x >= off) ? buf[threadIdx.x - off] : 0;
      __syncthreads();
      buf[threadIdx.x] += t;
      __syncthreads();
    }
    int excl = buf[threadIdx.x] - v + carry;  // carry read before update barrier
    if (i < n) { row_ptr[i] = excl; cursor[i] = excl; }
    __syncthreads();
    if (threadIdx.x == 255) carry += buf[255];
    __syncthreads();
  }
  if (threadIdx.x == 0) row_ptr[n] = carry;
}
__global__ void scatter_edges_kernel(const int* __restrict__ src, const int* __restrict__ dst,
                                     int* __restrict__ cursor, int* __restrict__ ssrc,
                                     int* __restrict__ sdst, int e) {
  int i = blockIdx.x * 256 + threadIdx.x;
  if (i < e) {
    int d = dst[i];
    int pos = atomicAdd(&cursor[d], 1);
    ssrc[pos] = src[i];
    sdst[pos] = d;
  }
}

// ---------------- small utility kernels ----------------
__global__ void bn_prep(const float* __restrict__ g, const float* __restrict__ b,
                        const float* __restrict__ m, const float* __restrict__ v,
                        float* __restrict__ scale, float* __restrict__ shift, int n) {
  int i = blockIdx.x * 256 + threadIdx.x;
  if (i < n) {
    float s = g[i] * rsqrtf(v[i] + 1e-5f);
    scale[i] = s;
    shift[i] = b[i] - m[i] * s;
  }
}
// out = (Q written) ? P + dec(Q) : 0   (empty segment -> 0, matches reference)
__global__ void combine_kernel(const unsigned* __restrict__ Q, const float* __restrict__ P,
                               float* __restrict__ H, int n) {
  int i = blockIdx.x * 256 + threadIdx.x;
  if (i < n) {
    unsigned e = Q[i];
    H[i] = e ? (P[i] + dec_f32(e)) : 0.f;
  }
}

// ---------------- input projection: rows 0 mod 4 use Wm/bm, else Wc/bc ----------------
__global__ void __launch_bounds__(256)
proj_kernel(const float* __restrict__ X, const float* __restrict__ Wm,
            const float* __restrict__ bm, const float* __restrict__ Wc,
            const float* __restrict__ bc, float* __restrict__ X0) {
  __shared__ float xs[4][IN_FEATS];
  int tid = threadIdx.x;
  int rowBase = blockIdx.x * 4;
  for (int idx = tid; idx < 4 * IN_FEATS; idx += 256) {
    int r = idx >> 9, k = idx & 511;
    xs[r][k] = X[(size_t)(rowBase + r) * IN_FEATS + k];
  }
  __syncthreads();
  int r = tid >> 6, j = tid & 63;  // r==0 <=> global row % 4 == 0 (wave-uniform)
  const float* W = (r == 0) ? Wm : Wc;
  float acc = 0.f;
#pragma unroll 8
  for (int k = 0; k < IN_FEATS; ++k) acc = fmaf(xs[r][k], W[k * 64 + j], acc);
  float b = (r == 0) ? bm[j] : bc[j];
  X0[(size_t)(rowBase + r) * 64 + j] = acc + b;
}

// ------- GCN dense part: Hs = (X@W)*dinv[row] ; Ginit = bias + Hs*dinv (self-loop) -------
template <int K, int F>
__global__ void __launch_bounds__(256)
gcn_gemm_kernel(const float* __restrict__ X, const float* __restrict__ W,
                const float* __restrict__ bias, const float* __restrict__ dinv,
                float* __restrict__ Hout, float* __restrict__ Ginit, int n) {
  __shared__ float Xs[64][K + 1];
  __shared__ float Ws[K][65];
  int tid = threadIdx.x;
  int rowBase = blockIdx.x * 64;
  int colBase = blockIdx.y * 64;
  for (int idx = tid; idx < 64 * K; idx += 256) {
    int r = idx / K, k = idx % K;
    int row = rowBase + r;
    Xs[r][k] = (row < n) ? X[(size_t)row * K + k] : 0.f;
  }
  for (int idx = tid; idx < K * 64; idx += 256) {
    int k = idx >> 6, c = idx & 63;
    Ws[k][c] = W[(size_t)k * F + colBase + c];
  }
  __syncthreads();
  int tx = tid & 15, ty = tid >> 4;
  float acc[4][4] = {};
  for (int k = 0; k < K; ++k) {
    float a[4], b[4];
#pragma unroll
    for (int r = 0; r < 4; ++r) a[r] = Xs[ty * 4 + r][k];
#pragma unroll
    for (int c = 0; c < 4; ++c) b[c] = Ws[k][tx * 4 + c];
#pragma unroll
    for (int r = 0; r < 4; ++r)
#pragma unroll
      for (int c = 0; c < 4; ++c) acc[r][c] = fmaf(a[r], b[c], acc[r][c]);
  }
#pragma unroll
  for (int r = 0; r < 4; ++r) {
    int row = rowBase + ty * 4 + r;
    if (row < n) {
      float di = dinv[row];
#pragma unroll
      for (int c = 0; c < 4; ++c) {
        int col = colBase + tx * 4 + c;
        float v = acc[r][c] * di;  // pre-scale by dinv[src] for the gather
        Hout[(size_t)row * F + col] = v;
        Ginit[(size_t)row * F + col] = fmaf(v, di, bias[col]);
      }
    }
  }
}

// ------- GCN aggregation (CSR gather, no atomics): G[d] = Ginit[d] + dinv[d]*sum Hs[src] -------
template <int F>
__global__ void __launch_bounds__(256)
gcn_gather_kernel(const float* __restrict__ Hs, const int* __restrict__ row_ptr,
                  const int* __restrict__ ssrc, const float* __restrict__ dinv,
                  float* __restrict__ G, int n) {
  int g = blockIdx.x * 256 + threadIdx.x;
  int d = g / F, col = g % F;  // F is pow2; wave-uniform d (F>=64)
  if (d >= n) return;
  int beg = row_ptr[d], end = row_ptr[d + 1];
  float acc = 0.f;
  int e = beg;
  for (; e + 1 < end; e += 2) {  // 2 independent loads in flight
    int s0 = ssrc[e], s1 = ssrc[e + 1];
    acc += Hs[(size_t)s0 * F + col];
    acc += Hs[(size_t)s1 * F + col];
  }
  if (e < end) acc += Hs[(size_t)ssrc[e] * F + col];
  G[(size_t)d * F + col] += dinv[d] * acc;  // in-place over Ginit
}

// ---------------- EdgeConv split GEMM ----------------
// EdgeConv(feat=[x_d, x_s-x_d]) with elementwise BN+ReLU splits as
//   h_e = ReLU(BN_top(x_d))@W_top + ReLU(BN_bot(x_s-x_d))@W_bot
// and segment_max_d(h) = P[d] + segment_max_d(Q_e), P per-node, Q per-edge.
// EDGE=true computes Q over dst-SORTED edges -> run-merged atomicMax epilogue.
template <int C, bool EDGE>
__global__ void __launch_bounds__(256, 3)
ec_gemm_kernel(const float* __restrict__ X, const int* __restrict__ src,
               const int* __restrict__ dst, const float* __restrict__ scale,
               const float* __restrict__ shift, const float* __restrict__ W,
               unsigned* __restrict__ outU, float* __restrict__ outP, int nrows) {
  __shared__ float As[128 * 32];  // row-major, col-group XOR-swizzled by (row>>3)&7
  __shared__ float Bs[32 * 128];  // row-major, col-group XOR-swizzled by kk&7
  __shared__ int se[128], de[128];
  const int tid = threadIdx.x;
  const int base = blockIdx.x * 128;
  if (EDGE && tid < 128) {
    se[tid] = src[base + tid];
    de[tid] = dst[base + tid];
  }
  __syncthreads();

  const int tx = tid & 15, ty = tid >> 4;
  const int sA = ty & 7;
  float acc[8][8] = {};

  for (int kc = 0; kc < C; kc += 32) {
    // ---- stage A: 128 rows x 32 k, BN+ReLU fused, float4 tasks ----
#pragma unroll
    for (int i = 0; i < 4; ++i) {
      int idx = i * 256 + tid;
      int e = idx >> 3, cg = idx & 7;  // row, 4-float col-group
      int kg = kc + cg * 4;
      float4 v;
      if (EDGE) {
        float4 a = *reinterpret_cast<const float4*>(X + (size_t)se[e] * C + kg);
        float4 b = *reinterpret_cast<const float4*>(X + (size_t)de[e] * C + kg);
        v = make_float4(a.x - b.x, a.y - b.y, a.z - b.z, a.w - b.w);
      } else {
        int row = base + e;
        if (row >= nrows) row = nrows - 1;  // clamp; epilogue guards stores
        v = *reinterpret_cast<const float4*>(X + (size_t)row * C + kg);
      }
      float4 sc = *reinterpret_cast<const float4*>(scale + kg);
      float4 sh = *reinterpret_cast<const float4*>(shift + kg);
      v.x = fmaxf(fmaf(v.x, sc.x, sh.x), 0.f);
      v.y = fmaxf(fmaf(v.y, sc.y, sh.y), 0.f);
      v.z = fmaxf(fmaf(v.z, sc.z, sh.z), 0.f);
      v.w = fmaxf(fmaf(v.w, sc.w, sh.w), 0.f);
      *reinterpret_cast<float4*>(&As[e * 32 + ((cg ^ ((e >> 3) & 7)) << 2)]) = v;
    }
    // ---- stage B: 32 k x 128 cols ----
#pragma unroll
    for (int i = 0; i < 4; ++i) {
      int idx = i * 256 + tid;
      int kk = idx >> 5, cg = idx & 31;
      *reinterpret_cast<float4*>(&Bs[kk * 128 + ((cg ^ (kk & 7)) << 2)]) =
          *reinterpret_cast<const float4*>(W + (size_t)(kc + kk) * 128 + cg * 4);
    }
    __syncthreads();
    // ---- compute: 8x8 per thread, all-b128 LDS reads ----
#pragma unroll
    for (int kk4 = 0; kk4 < 8; ++kk4) {
      float4 a[8];
#pragma unroll
      for (int r = 0; r < 8; ++r)
        a[r] = *reinterpret_cast<const float4*>(
            &As[(ty * 8 + r) * 32 + ((kk4 ^ sA) << 2)]);
#pragma unroll
      for (int w = 0; w < 4; ++w) {
        int kk = kk4 * 4 + w;
        int k7 = kk & 7;
        float4 b0 = *reinterpret_cast<const float4*>(
            &Bs[kk * 128 + ((tx ^ k7) << 2)]);  // cols tx*4..+3
        float4 b1 = *reinterpret_cast<const float4*>(
            &Bs[kk * 128 + (((tx + 16) ^ k7) << 2)]);  // cols 64+tx*4..+3
#pragma unroll
        for (int r = 0; r < 8; ++r) {
          float av = reinterpret_cast<const float*>(&a[r])[w];
          acc[r][0] = fmaf(av, b0.x, acc[r][0]);
          acc[r][1] = fmaf(av, b0.y, acc[r][1]);
          acc[r][2] = fmaf(av, b0.z, acc[r][2]);
          acc[r][3] = fmaf(av, b0.w, acc[r][3]);
          acc[r][4] = fmaf(av, b1.x, acc[r][4]);
          acc[r][5] = fmaf(av, b1.y, acc[r][5]);
          acc[r][6] = fmaf(av, b1.z, acc[r][6]);
          acc[r][7] = fmaf(av, b1.w, acc[r][7]);
        }
      }
    }
    __syncthreads();
  }

  // ---- epilogue ----
  if (EDGE) {
    // edges are dst-sorted: merge same-dst runs in registers, then flush.
    float m[8];
    int prev = de[ty * 8];
#pragma unroll
    for (int c = 0; c < 8; ++c) m[c] = acc[0][c];
#pragma unroll
    for (int r = 1; r < 8; ++r) {
      int d = de[ty * 8 + r];
      if (d != prev) {
        unsigned* p = outU + (size_t)prev * 128 + tx * 4;
#pragma unroll
        for (int c = 0; c < 4; ++c) atomicMax(p + c, enc_f32(m[c]));
#pragma unroll
        for (int c = 0; c < 4; ++c) atomicMax(p + 64 + c, enc_f32(m[4 + c]));
        prev = d;
#pragma unroll
        for (int c = 0; c < 8; ++c) m[c] = acc[r][c];
      } else {
#pragma unroll
        for (int c = 0; c < 8; ++c) m[c] = fmaxf(m[c], acc[r][c]);
      }
    }
    unsigned* p = outU + (size_t)prev * 128 + tx * 4;
#pragma unroll
    for (int c = 0; c < 4; ++c) atomicMax(p + c, enc_f32(m[c]));
#pragma unroll
    for (int c = 0; c < 4; ++c) atomicMax(p + 64 + c, enc_f32(m[4 + c]));
  } else {
#pragma unroll
    for (int r = 0; r < 8; ++r) {
      int row = base + ty * 8 + r;
      if (row < nrows) {
        *reinterpret_cast<float4*>(outP + (size_t)row * 128 + tx * 4) =
            make_float4(acc[r][0], acc[r][1], acc[r][2], acc[r][3]);
        *reinterpret_cast<float4*>(outP + (size_t)row * 128 + 64 + tx * 4) =
            make_float4(acc[r][4], acc[r][5], acc[r][6], acc[r][7]);
      }
    }
  }
}

// ---------------- final FC: out[i] = h[i,0:128] . Wfc + bfc ----------------
__global__ void __launch_bounds__(256)
fc_kernel(const float* __restrict__ Hf, const float* __restrict__ Wfc,
          const float* __restrict__ bfc, float* __restrict__ out, int n) {
  int g = blockIdx.x * 256 + threadIdx.x;
  int node = g >> 6, lane = g & 63;
  if (node >= n) return;
  float v = fmaf(Hf[(size_t)node * 128 + lane], Wfc[lane],
                 Hf[(size_t)node * 128 + 64 + lane] * Wfc[64 + lane]);
#pragma unroll
  for (int off = 32; off > 0; off >>= 1) v += __shfl_down(v, off);
  if (lane == 0) out[node] = v + bfc[0];
}

extern "C" void kernel_launch(void* const* d_in, const int* in_sizes, int n_in,
                              void* d_out, int out_size, void* d_ws, size_t ws_size,
                              hipStream_t stream) {
  const float* x   = (const float*)d_in[0];
  const int*   ei  = (const int*)d_in[1];
  const float* Wm  = (const float*)d_in[2];
  const float* bm  = (const float*)d_in[3];
  const float* Wc  = (const float*)d_in[4];
  const float* bc  = (const float*)d_in[5];
  const float* Wg1 = (const float*)d_in[6];
  const float* bg1 = (const float*)d_in[7];
  const float* Wg2 = (const float*)d_in[8];
  const float* bg2 = (const float*)d_in[9];
  const float* Wg3 = (const float*)d_in[10];
  const float* bg3 = (const float*)d_in[11];
  const float* e1g = (const float*)d_in[12];
  const float* e1b = (const float*)d_in[13];
  const float* e1m = (const float*)d_in[14];
  const float* e1v = (const float*)d_in[15];
  const float* e1W = (const float*)d_in[16];
  const float* e2g = (const float*)d_in[17];
  const float* e2b = (const float*)d_in[18];
  const float* e2m = (const float*)d_in[19];
  const float* e2v = (const float*)d_in[20];
  const float* e2W = (const float*)d_in[21];
  const float* e3g = (const float*)d_in[22];
  const float* e3b = (const float*)d_in[23];
  const float* e3m = (const float*)d_in[24];
  const float* e3v = (const float*)d_in[25];
  const float* e3W = (const float*)d_in[26];
  const float* Wfc = (const float*)d_in[27];
  const float* bfc = (const float*)d_in[28];

  const int* src = ei;            // edge_index[0]
  const int* dst = ei + N_EDGES;  // edge_index[1]

  // workspace layout (floats): same ~67 MB footprint as rounds 1-2
  float* ws   = (float*)d_ws;
  float* dinv = ws;                                  // N
  float* x0   = dinv + N_NODES;                      // N*64
  float* hbuf = x0 + (size_t)N_NODES * 64;           // N*256 (GCN H, then P|Q)
  float* gA   = hbuf + (size_t)N_NODES * 256;        // N*256
  float* gB   = gA + (size_t)N_NODES * 256;          // N*256 (only first half used as data)
  float* sc1  = gB + (size_t)N_NODES * 256;          // 512
  float* sh1  = sc1 + 512;                           // 512
  float* sc2  = sh1 + 512;                           // 256
  float* sh2  = sc2 + 256;                           // 256
  float* sc3  = sh2 + 256;                           // 256
  float* sh3  = sc3 + 256;                           // 256

  float*    Pbuf = hbuf;                             // N*128 (after GCN, hbuf is free)
  unsigned* Qbuf = (unsigned*)(hbuf + (size_t)N_NODES * 128);  // N*128

  // CSR arrays live in gB's never-used second half (2.8 MB of 10.2 MB)
  int* cnt     = (int*)(gB + (size_t)N_NODES * 128);  // N
  int* row_ptr = cnt + N_NODES;                       // N+1
  int* cursor  = row_ptr + N_NODES + 1;               // N
  int* ssrc    = cursor + N_NODES;                    // E (dst-sorted src)
  int* sdst    = ssrc + N_EDGES;                      // E (sorted dst)

  // ---- CSR build (counting sort by dst) + dinv ----
  hipMemsetAsync(cnt, 0, N_NODES * sizeof(int), stream);
  hist_kernel<<<N_EDGES / 256, 256, 0, stream>>>(dst, cnt, N_EDGES);
  dinv_kernel<<<79, 256, 0, stream>>>(cnt, dinv, N_NODES);
  scan_kernel<<<1, 256, 0, stream>>>(cnt, row_ptr, cursor, N_NODES);
  scatter_edges_kernel<<<N_EDGES / 256, 256, 0, stream>>>(src, dst, cursor, ssrc, sdst,
                                                          N_EDGES);

  // BN folded scale/shift
  bn_prep<<<2, 256, 0, stream>>>(e1g, e1b, e1m, e1v, sc1, sh1, 512);
  bn_prep<<<1, 256, 0, stream>>>(e2g, e2b, e2m, e2v, sc2, sh2, 256);
  bn_prep<<<1, 256, 0, stream>>>(e3g, e3b, e3m, e3v, sc3, sh3, 256);

  // x0 projection (row%4 selects Wm vs Wc)
  proj_kernel<<<N_NODES / 4, 256, 0, stream>>>(x, Wm, bm, Wc, bc, x0);

  // GCN layers: gemm (Hs + self-loop init) then CSR gather (no atomics)
  dim3 grid2(313, 2), grid4(313, 4);
  gcn_gemm_kernel<64, 128><<<grid2, 256, 0, stream>>>(x0, Wg1, bg1, dinv, hbuf, gA, N_NODES);
  gcn_gather_kernel<128><<<N_NODES * 128 / 256, 256, 0, stream>>>(hbuf, row_ptr, ssrc, dinv,
                                                                  gA, N_NODES);
  gcn_gemm_kernel<128, 128><<<grid2, 256, 0, stream>>>(gA, Wg2, bg2, dinv, hbuf, gB, N_NODES);
  gcn_gather_kernel<128><<<N_NODES * 128 / 256, 256, 0, stream>>>(hbuf, row_ptr, ssrc, dinv,
                                                                  gB, N_NODES);
  gcn_gemm_kernel<128, 256><<<grid4, 256, 0, stream>>>(gB, Wg3, bg3, dinv, hbuf, gA, N_NODES);
  gcn_gather_kernel<256><<<N_NODES * 256 / 256, 256, 0, stream>>>(hbuf, row_ptr, ssrc, dinv,
                                                                  gA, N_NODES);

  const int NODE_BLOCKS = (N_NODES + 127) / 128;  // 157
  const int EDGE_BLOCKS = N_EDGES / 128;          // 2500
  const int NB_ELEM     = N_NODES * 128 / 256;    // 10000

  // EdgeConv 1: input gA [N,256] -> gB [N,128]
  hipMemsetAsync(Qbuf, 0, (size_t)N_NODES * 128 * 4, stream);
  ec_gemm_kernel<256, false><<<NODE_BLOCKS, 256, 0, stream>>>(
      gA, nullptr, nullptr, sc1, sh1, e1W, nullptr, Pbuf, N_NODES);
  ec_gemm_kernel<256, true><<<EDGE_BLOCKS, 256, 0, stream>>>(
      gA, ssrc, sdst, sc1 + 256, sh1 + 256, e1W + 256 * 128, Qbuf, nullptr, N_NODES);
  combine_kernel<<<NB_ELEM, 256, 0, stream>>>(Qbuf, Pbuf, gB, N_NODES * 128);

  // EdgeConv 2: input gB [N,128] -> gA [N,128]
  hipMemsetAsync(Qbuf, 0, (size_t)N_NODES * 128 * 4, stream);
  ec_gemm_kernel<128, false><<<NODE_BLOCKS, 256, 0, stream>>>(
      gB, nullptr, nullptr, sc2, sh2, e2W, nullptr, Pbuf, N_NODES);
  ec_gemm_kernel<128, true><<<EDGE_BLOCKS, 256, 0, stream>>>(
      gB, ssrc, sdst, sc2 + 128, sh2 + 128, e2W + 128 * 128, Qbuf, nullptr, N_NODES);
  combine_kernel<<<NB_ELEM, 256, 0, stream>>>(Qbuf, Pbuf, gA, N_NODES * 128);

  // EdgeConv 3: input gA [N,128] -> gB [N,128]
  hipMemsetAsync(Qbuf, 0, (size_t)N_NODES * 128 * 4, stream);
  ec_gemm_kernel<128, false><<<NODE_BLOCKS, 256, 0, stream>>>(
      gA, nullptr, nullptr, sc3, sh3, e3W, nullptr, Pbuf, N_NODES);
  ec_gemm_kernel<128, true><<<EDGE_BLOCKS, 256, 0, stream>>>(
      gA, ssrc, sdst, sc3 + 128, sh3 + 128, e3W + 128 * 128, Qbuf, nullptr, N_NODES);
  combine_kernel<<<NB_ELEM, 256, 0, stream>>>(Qbuf, Pbuf, gB, N_NODES * 128);

  // final FC
  fc_kernel<<<N_NODES * 64 / 256, 256, 0, stream>>>(gB, Wfc, bfc, (float*)d_out, N_NODES);
}

// Round 4
// 1083.582 us; speedup vs baseline: 3.4053x; 1.1695x over previous
//
#include <hip/hip_runtime.h>

#define DEVINL __device__ __forceinline__

constexpr int N_NODES  = 20000;
constexpr int N_EDGES  = 320000;
constexpr int IN_FEATS = 512;

static_assert(N_EDGES % 128 == 0, "edge tiling assumes E % 128 == 0");
static_assert(N_NODES % 16 == 0, "proj assumes N % 16 == 0");

typedef __attribute__((ext_vector_type(8))) short short8;  // 8 bf16 = 4 VGPR
typedef __attribute__((ext_vector_type(4))) float f32x4;   // MFMA acc

// ---- monotone float<->uint order encoding (for atomicMax-based segment_max) ----
DEVINL unsigned enc_f32(float v) {
  unsigned b = __float_as_uint(v);
  return (b & 0x80000000u) ? ~b : (b | 0x80000000u);
}
DEVINL float dec_f32(unsigned e) {
  unsigned b = (e & 0x80000000u) ? (e & 0x7FFFFFFFu) : ~e;
  return __uint_as_float(b);
}

// ---- bf16 split helpers (A = hi + lo, each RNE bf16) ----
DEVINL unsigned short bf16_rne(float f) {
  unsigned u = __float_as_uint(f);
  u += 0x7FFFu + ((u >> 16) & 1u);
  return (unsigned short)(u >> 16);
}
DEVINL void split_bf16(float v, unsigned short& h, unsigned short& l) {
  h = bf16_rne(v);
  float hf = __uint_as_float((unsigned)h << 16);
  l = bf16_rne(v - hf);
}
DEVINL unsigned long long pack4(unsigned short a, unsigned short b, unsigned short c,
                                unsigned short d) {
  return (unsigned long long)a | ((unsigned long long)b << 16) |
         ((unsigned long long)c << 32) | ((unsigned long long)d << 48);
}

// ---------------- CSR build (counting sort by dst) ----------------
__global__ void hist_kernel(const int* __restrict__ dst, int* __restrict__ cnt, int e) {
  int i = blockIdx.x * 256 + threadIdx.x;
  if (i < e) atomicAdd(&cnt[dst[i]], 1);
}
__global__ void dinv_kernel(const int* __restrict__ cnt, float* __restrict__ dinv, int n) {
  int i = blockIdx.x * 256 + threadIdx.x;
  if (i < n) dinv[i] = rsqrtf((float)cnt[i] + 1.0f);  // +1 self-loop
}
__global__ void __launch_bounds__(256)
scan_kernel(const int* __restrict__ cnt, int* __restrict__ row_ptr,
            int* __restrict__ cursor, int n) {
  __shared__ int buf[256];
  __shared__ int carry;
  if (threadIdx.x == 0) carry = 0;
  __syncthreads();
  for (int base = 0; base < n; base += 256) {
    int i = base + threadIdx.x;
    int v = (i < n) ? cnt[i] : 0;
    buf[threadIdx.x] = v;
    __syncthreads();
    for (int off = 1; off < 256; off <<= 1) {
      int t = (threadIdx.x >= off) ? buf[threadIdx.x - off] : 0;
      __syncthreads();
      buf[threadIdx.x] += t;
      __syncthreads();
    }
    int excl = buf[threadIdx.x] - v + carry;
    if (i < n) { row_ptr[i] = excl; cursor[i] = excl; }
    __syncthreads();
    if (threadIdx.x == 255) carry += buf[255];
    __syncthreads();
  }
  if (threadIdx.x == 0) row_ptr[n] = carry;
}
__global__ void scatter_edges_kernel(const int* __restrict__ src, const int* __restrict__ dst,
                                     int* __restrict__ cursor, int* __restrict__ ssrc,
                                     int* __restrict__ sdst, int e) {
  int i = blockIdx.x * 256 + threadIdx.x;
  if (i < e) {
    int d = dst[i];
    int pos = atomicAdd(&cursor[d], 1);
    ssrc[pos] = src[i];
    sdst[pos] = d;
  }
}

// ---------------- small utility kernels ----------------
__global__ void bn_prep(const float* __restrict__ g, const float* __restrict__ b,
                        const float* __restrict__ m, const float* __restrict__ v,
                        float* __restrict__ scale, float* __restrict__ shift, int n) {
  int i = blockIdx.x * 256 + threadIdx.x;
  if (i < n) {
    float s = g[i] * rsqrtf(v[i] + 1e-5f);
    scale[i] = s;
    shift[i] = b[i] - m[i] * s;
  }
}
__global__ void combine_kernel(const unsigned* __restrict__ Q, const float* __restrict__ P,
                               float* __restrict__ H, int n) {
  int i = blockIdx.x * 256 + threadIdx.x;
  if (i < n) {
    unsigned e = Q[i];
    H[i] = e ? (P[i] + dec_f32(e)) : 0.f;
  }
}

// ---- W pre-transform into the LDS frag image (split bf16 hi/lo) ----
// Layout per 32-k chunk (16 KB): hi 8 KB then lo 8 KB.  Frag index:
// frag = (ct*4 + kq)*16 + n  (ct=c>>4, kq=(k>>3)&3, n=c&15), j = k&7.
__global__ void wfrag_kernel(const float* __restrict__ W, unsigned short* __restrict__ out,
                             int total) {  // total = C*128
  int e = blockIdx.x * 256 + threadIdx.x;
  if (e >= total) return;
  int k = e >> 7, c = e & 127;
  unsigned short h, l;
  split_bf16(W[e], h, l);
  int chunk = k >> 5, kq = (k >> 3) & 3, j = k & 7, ct = c >> 4, n = c & 15;
  int frag = (ct * 4 + kq) * 16 + n;
  size_t o = (size_t)chunk * 8192 + frag * 8 + j;
  out[o] = h;
  out[o + 4096] = l;
}

// ---------------- input projection: rows 0 mod 4 use Wm/bm, else Wc/bc ----------------
// 16 rows per block; each thread handles 4 rows of the same residue class so the
// W column load is amortized 4x (L2 W-traffic /4 vs round-3 version).
__global__ void __launch_bounds__(256)
proj_kernel(const float* __restrict__ X, const float* __restrict__ Wm,
            const float* __restrict__ bm, const float* __restrict__ Wc,
            const float* __restrict__ bc, float* __restrict__ X0) {
  __shared__ float xs[16][IN_FEATS];  // 32 KB
  int tid = threadIdx.x;
  int rowBase = blockIdx.x * 16;
  for (int i = 0; i < 8; ++i) {
    int idx = i * 256 + tid;           // 2048 float4 tasks
    int r = idx >> 7, kq = idx & 127;
    *reinterpret_cast<float4*>(&xs[r][kq * 4]) =
        *reinterpret_cast<const float4*>(X + (size_t)(rowBase + r) * IN_FEATS + kq * 4);
  }
  __syncthreads();
  int r4 = tid >> 6;  // residue class (wave-uniform); wave0 -> Wm, else Wc
  int j = tid & 63;
  const float* W = (r4 == 0) ? Wm : Wc;
  float a0 = 0.f, a1 = 0.f, a2 = 0.f, a3 = 0.f;
#pragma unroll 4
  for (int k = 0; k < IN_FEATS; ++k) {
    float w = W[k * 64 + j];
    a0 = fmaf(xs[r4][k], w, a0);
    a1 = fmaf(xs[r4 + 4][k], w, a1);
    a2 = fmaf(xs[r4 + 8][k], w, a2);
    a3 = fmaf(xs[r4 + 12][k], w, a3);
  }
  float b = (r4 == 0) ? bm[j] : bc[j];
  X0[(size_t)(rowBase + r4) * 64 + j] = a0 + b;
  X0[(size_t)(rowBase + r4 + 4) * 64 + j] = a1 + b;
  X0[(size_t)(rowBase + r4 + 8) * 64 + j] = a2 + b;
  X0[(size_t)(rowBase + r4 + 12) * 64 + j] = a3 + b;
}

// ------- GCN dense part: Hs = (X@W)*dinv[row] ; Ginit = bias + Hs*dinv (self-loop) -------
template <int K, int F>
__global__ void __launch_bounds__(256)
gcn_gemm_kernel(const float* __restrict__ X, const float* __restrict__ W,
                const float* __restrict__ bias, const float* __restrict__ dinv,
                float* __restrict__ Hout, float* __restrict__ Ginit, int n) {
  __shared__ float Xs[64][K + 1];
  __shared__ float Ws[K][65];
  int tid = threadIdx.x;
  int rowBase = blockIdx.x * 64;
  int colBase = blockIdx.y * 64;
  for (int idx = tid; idx < 64 * K; idx += 256) {
    int r = idx / K, k = idx % K;
    int row = rowBase + r;
    Xs[r][k] = (row < n) ? X[(size_t)row * K + k] : 0.f;
  }
  for (int idx = tid; idx < K * 64; idx += 256) {
    int k = idx >> 6, c = idx & 63;
    Ws[k][c] = W[(size_t)k * F + colBase + c];
  }
  __syncthreads();
  int tx = tid & 15, ty = tid >> 4;
  float acc[4][4] = {};
  for (int k = 0; k < K; ++k) {
    float a[4], b[4];
#pragma unroll
    for (int r = 0; r < 4; ++r) a[r] = Xs[ty * 4 + r][k];
#pragma unroll
    for (int c = 0; c < 4; ++c) b[c] = Ws[k][tx * 4 + c];
#pragma unroll
    for (int r = 0; r < 4; ++r)
#pragma unroll
      for (int c = 0; c < 4; ++c) acc[r][c] = fmaf(a[r], b[c], acc[r][c]);
  }
#pragma unroll
  for (int r = 0; r < 4; ++r) {
    int row = rowBase + ty * 4 + r;
    if (row < n) {
      float di = dinv[row];
#pragma unroll
      for (int c = 0; c < 4; ++c) {
        int col = colBase + tx * 4 + c;
        float v = acc[r][c] * di;
        Hout[(size_t)row * F + col] = v;
        Ginit[(size_t)row * F + col] = fmaf(v, di, bias[col]);
      }
    }
  }
}

// ------- GCN aggregation (CSR gather): G[d] = Ginit[d] + dinv[d]*sum Hs[src] -------
template <int F>
__global__ void __launch_bounds__(256)
gcn_gather_kernel(const float* __restrict__ Hs, const int* __restrict__ row_ptr,
                  const int* __restrict__ ssrc, const float* __restrict__ dinv,
                  float* __restrict__ G, int n) {
  int g = blockIdx.x * 256 + threadIdx.x;
  int d = g / F, col = g % F;
  if (d >= n) return;
  int beg = row_ptr[d], end = row_ptr[d + 1];
  float acc = 0.f;
  int e = beg;
  for (; e + 1 < end; e += 2) {
    int s0 = ssrc[e], s1 = ssrc[e + 1];
    acc += Hs[(size_t)s0 * F + col];
    acc += Hs[(size_t)s1 * F + col];
  }
  if (e < end) acc += Hs[(size_t)ssrc[e] * F + col];
  G[(size_t)d * F + col] += dinv[d] * acc;
}

// ---------------- EdgeConv split-bf16 MFMA GEMM ----------------
// D[128 rows x 128 cols] per block; A = BN+ReLU(features) split to bf16 hi/lo,
// B pre-transformed by wfrag_kernel.  3 MFMAs emulate fp32: AhBh + AhBl + AlBh.
// 4 waves in a 2x2 grid of 64x64 tiles; v_mfma_f32_16x16x32_bf16.
// A-frag LDS layout is frag-major: frag fi = (g*4+q)*16+m at byte fi*16 -> a
// wave's frag read is 1024 contiguous bytes (conflict-free b128).
template <int C, bool EDGE>
__global__ void __launch_bounds__(256, 3)
ec_mfma_kernel(const float* __restrict__ X, const int* __restrict__ src,
               const int* __restrict__ dst, const float* __restrict__ scale,
               const float* __restrict__ shift, const unsigned short* __restrict__ Bfrag,
               unsigned* __restrict__ outU, float* __restrict__ outP, int nrows) {
  __shared__ unsigned short Ahi[4096];  // 128 rows x 32 k, frag-major (8 KB)
  __shared__ unsigned short Alo[4096];
  __shared__ unsigned short Bbuf[8192];  // hi 4096 then lo 4096 (16 KB)
  __shared__ int se[128], de[128];
  const int tid = threadIdx.x;
  const int base = blockIdx.x * 128;
  if (EDGE && tid < 128) {
    se[tid] = src[base + tid];
    de[tid] = dst[base + tid];
  }
  __syncthreads();

  const int lane = tid & 63;
  const int wv = tid >> 6;
  const int q = lane >> 4, mn = lane & 15;
  const int gbase = (wv & 1) * 4;    // 16-row group base (wave covers 64 rows)
  const int ctbase = (wv >> 1) * 4;  // 16-col tile base (wave covers 64 cols)

  f32x4 acc[4][4];  // [ct][g]
#pragma unroll
  for (int ct = 0; ct < 4; ++ct)
#pragma unroll
    for (int g = 0; g < 4; ++g) acc[ct][g] = (f32x4)0.f;

  for (int kc = 0; kc < C; kc += 32) {
    // ---- stage A: 1024 float4 tasks (BN+ReLU+split), write b64 hi/lo ----
#pragma unroll
    for (int i = 0; i < 4; ++i) {
      int idx = i * 256 + tid;
      int row = idx >> 3, cg = idx & 7;
      int k0 = cg * 4;
      float4 v;
      if (EDGE) {
        float4 a = *reinterpret_cast<const float4*>(X + (size_t)se[row] * C + kc + k0);
        float4 b = *reinterpret_cast<const float4*>(X + (size_t)de[row] * C + kc + k0);
        v = make_float4(a.x - b.x, a.y - b.y, a.z - b.z, a.w - b.w);
      } else {
        int r = base + row;
        if (r >= nrows) r = nrows - 1;  // clamp; epilogue guards stores
        v = *reinterpret_cast<const float4*>(X + (size_t)r * C + kc + k0);
      }
      float4 sc = *reinterpret_cast<const float4*>(scale + kc + k0);
      float4 sh = *reinterpret_cast<const float4*>(shift + kc + k0);
      float f0 = fmaxf(fmaf(v.x, sc.x, sh.x), 0.f);
      float f1 = fmaxf(fmaf(v.y, sc.y, sh.y), 0.f);
      float f2 = fmaxf(fmaf(v.z, sc.z, sh.z), 0.f);
      float f3 = fmaxf(fmaf(v.w, sc.w, sh.w), 0.f);
      unsigned short h0, h1, h2, h3, l0, l1, l2, l3;
      split_bf16(f0, h0, l0);
      split_bf16(f1, h1, l1);
      split_bf16(f2, h2, l2);
      split_bf16(f3, h3, l3);
      int g = row >> 4, m = row & 15;
      int frag = (g * 4 + (cg >> 1)) * 16 + m;
      int uidx = frag * 8 + (cg & 1) * 4;  // 8-byte aligned
      *reinterpret_cast<unsigned long long*>(&Ahi[uidx]) = pack4(h0, h1, h2, h3);
      *reinterpret_cast<unsigned long long*>(&Alo[uidx]) = pack4(l0, l1, l2, l3);
    }
    // ---- stage B: straight 16 KB copy of the pre-transformed chunk ----
    {
      const float4* bsrc = reinterpret_cast<const float4*>(Bfrag + (size_t)(kc >> 5) * 8192);
      float4* bdst = reinterpret_cast<float4*>(Bbuf);
#pragma unroll
      for (int i = 0; i < 4; ++i) {
        int idx = i * 256 + tid;
        bdst[idx] = bsrc[idx];
      }
    }
    __syncthreads();
    // ---- compute: load frags (contiguous b128), 48 MFMAs ----
    short8 ah[4], al[4];
#pragma unroll
    for (int g = 0; g < 4; ++g) {
      int fi = (gbase + g) * 64 + lane;
      ah[g] = *reinterpret_cast<const short8*>(&Ahi[fi * 8]);
      al[g] = *reinterpret_cast<const short8*>(&Alo[fi * 8]);
    }
#pragma unroll
    for (int ct = 0; ct < 4; ++ct) {
      int fi = (ctbase + ct) * 64 + lane;
      short8 bh = *reinterpret_cast<const short8*>(&Bbuf[fi * 8]);
      short8 bl = *reinterpret_cast<const short8*>(&Bbuf[4096 + fi * 8]);
#pragma unroll
      for (int g = 0; g < 4; ++g)
        acc[ct][g] = __builtin_amdgcn_mfma_f32_16x16x32_bf16(ah[g], bh, acc[ct][g], 0, 0, 0);
#pragma unroll
      for (int g = 0; g < 4; ++g)
        acc[ct][g] = __builtin_amdgcn_mfma_f32_16x16x32_bf16(ah[g], bl, acc[ct][g], 0, 0, 0);
#pragma unroll
      for (int g = 0; g < 4; ++g)
        acc[ct][g] = __builtin_amdgcn_mfma_f32_16x16x32_bf16(al[g], bh, acc[ct][g], 0, 0, 0);
    }
    __syncthreads();
  }

  // ---- epilogue: C/D layout is col=lane&15, row=q*4+reg ----
  if (EDGE) {
#pragma unroll
    for (int ct = 0; ct < 4; ++ct) {
      int f = (ctbase + ct) * 16 + mn;
      float mv = 0.f;
      int prev = -1;
#pragma unroll
      for (int g = 0; g < 4; ++g) {
        int e0 = (gbase + g) * 16 + q * 4;
#pragma unroll
        for (int r = 0; r < 4; ++r) {
          int d = de[e0 + r];
          float v = acc[ct][g][r];
          if (prev < 0) {
            prev = d; mv = v;
          } else if (d == prev) {
            mv = fmaxf(mv, v);
          } else {
            atomicMax(&outU[(size_t)prev * 128 + f], enc_f32(mv));
            prev = d; mv = v;
          }
        }
      }
      atomicMax(&outU[(size_t)prev * 128 + f], enc_f32(mv));
    }
  } else {
#pragma unroll
    for (int ct = 0; ct < 4; ++ct) {
      int f = (ctbase + ct) * 16 + mn;
#pragma unroll
      for (int g = 0; g < 4; ++g) {
        int r0 = base + (gbase + g) * 16 + q * 4;
#pragma unroll
        for (int r = 0; r < 4; ++r) {
          int row = r0 + r;
          if (row < nrows) outP[(size_t)row * 128 + f] = acc[ct][g][r];
        }
      }
    }
  }
}

// ---------------- final FC: out[i] = h[i,0:128] . Wfc + bfc ----------------
__global__ void __launch_bounds__(256)
fc_kernel(const float* __restrict__ Hf, const float* __restrict__ Wfc,
          const float* __restrict__ bfc, float* __restrict__ out, int n) {
  int g = blockIdx.x * 256 + threadIdx.x;
  int node = g >> 6, lane = g & 63;
  if (node >= n) return;
  float v = fmaf(Hf[(size_t)node * 128 + lane], Wfc[lane],
                 Hf[(size_t)node * 128 + 64 + lane] * Wfc[64 + lane]);
#pragma unroll
  for (int off = 32; off > 0; off >>= 1) v += __shfl_down(v, off);
  if (lane == 0) out[node] = v + bfc[0];
}

extern "C" void kernel_launch(void* const* d_in, const int* in_sizes, int n_in,
                              void* d_out, int out_size, void* d_ws, size_t ws_size,
                              hipStream_t stream) {
  const float* x   = (const float*)d_in[0];
  const int*   ei  = (const int*)d_in[1];
  const float* Wm  = (const float*)d_in[2];
  const float* bm  = (const float*)d_in[3];
  const float* Wc  = (const float*)d_in[4];
  const float* bc  = (const float*)d_in[5];
  const float* Wg1 = (const float*)d_in[6];
  const float* bg1 = (const float*)d_in[7];
  const float* Wg2 = (const float*)d_in[8];
  const float* bg2 = (const float*)d_in[9];
  const float* Wg3 = (const float*)d_in[10];
  const float* bg3 = (const float*)d_in[11];
  const float* e1g = (const float*)d_in[12];
  const float* e1b = (const float*)d_in[13];
  const float* e1m = (const float*)d_in[14];
  const float* e1v = (const float*)d_in[15];
  const float* e1W = (const float*)d_in[16];
  const float* e2g = (const float*)d_in[17];
  const float* e2b = (const float*)d_in[18];
  const float* e2m = (const float*)d_in[19];
  const float* e2v = (const float*)d_in[20];
  const float* e2W = (const float*)d_in[21];
  const float* e3g = (const float*)d_in[22];
  const float* e3b = (const float*)d_in[23];
  const float* e3m = (const float*)d_in[24];
  const float* e3v = (const float*)d_in[25];
  const float* e3W = (const float*)d_in[26];
  const float* Wfc = (const float*)d_in[27];
  const float* bfc = (const float*)d_in[28];

  const int* src = ei;
  const int* dst = ei + N_EDGES;

  // workspace layout (floats): ~67.3 MB total
  float* ws   = (float*)d_ws;
  float* dinv = ws;                                  // N
  float* x0   = dinv + N_NODES;                      // N*64
  float* hbuf = x0 + (size_t)N_NODES * 64;           // N*256 (GCN H, then P|Q)
  float* gA   = hbuf + (size_t)N_NODES * 256;        // N*256
  float* gB   = gA + (size_t)N_NODES * 256;          // N*256 (data in first half)
  float* sc1  = gB + (size_t)N_NODES * 256;          // 512
  float* sh1  = sc1 + 512;
  float* sc2  = sh1 + 512;                           // 256
  float* sh2  = sc2 + 256;
  float* sc3  = sh2 + 256;
  float* sh3  = sc3 + 256;
  // pre-transformed W frag images (split bf16): 512 KB total
  unsigned short* bf1p = (unsigned short*)(sh3 + 256);  // 256*128*2 ushort = 128 KB
  unsigned short* bf1q = bf1p + 65536;
  unsigned short* bf2p = bf1q + 65536;                  // 128*128*2 = 64 KB
  unsigned short* bf2q = bf2p + 32768;
  unsigned short* bf3p = bf2q + 32768;
  unsigned short* bf3q = bf3p + 32768;

  float*    Pbuf = hbuf;                                        // N*128
  unsigned* Qbuf = (unsigned*)(hbuf + (size_t)N_NODES * 128);   // N*128

  // CSR arrays in gB's second half (data region is only the first N*128)
  int* cnt     = (int*)(gB + (size_t)N_NODES * 128);
  int* row_ptr = cnt + N_NODES;
  int* cursor  = row_ptr + N_NODES + 1;
  int* ssrc    = cursor + N_NODES;  // E
  int* sdst    = ssrc + N_EDGES;    // E

  // ---- CSR build + dinv ----
  hipMemsetAsync(cnt, 0, N_NODES * sizeof(int), stream);
  hist_kernel<<<N_EDGES / 256, 256, 0, stream>>>(dst, cnt, N_EDGES);
  dinv_kernel<<<79, 256, 0, stream>>>(cnt, dinv, N_NODES);
  scan_kernel<<<1, 256, 0, stream>>>(cnt, row_ptr, cursor, N_NODES);
  scatter_edges_kernel<<<N_EDGES / 256, 256, 0, stream>>>(src, dst, cursor, ssrc, sdst,
                                                          N_EDGES);

  // BN folded scale/shift
  bn_prep<<<2, 256, 0, stream>>>(e1g, e1b, e1m, e1v, sc1, sh1, 512);
  bn_prep<<<1, 256, 0, stream>>>(e2g, e2b, e2m, e2v, sc2, sh2, 256);
  bn_prep<<<1, 256, 0, stream>>>(e3g, e3b, e3m, e3v, sc3, sh3, 256);

  // W frag pre-transforms (P = top half rows [0,C), Q = bottom half rows [C,2C))
  wfrag_kernel<<<128, 256, 0, stream>>>(e1W, bf1p, 256 * 128);
  wfrag_kernel<<<128, 256, 0, stream>>>(e1W + 256 * 128, bf1q, 256 * 128);
  wfrag_kernel<<<64, 256, 0, stream>>>(e2W, bf2p, 128 * 128);
  wfrag_kernel<<<64, 256, 0, stream>>>(e2W + 128 * 128, bf2q, 128 * 128);
  wfrag_kernel<<<64, 256, 0, stream>>>(e3W, bf3p, 128 * 128);
  wfrag_kernel<<<64, 256, 0, stream>>>(e3W + 128 * 128, bf3q, 128 * 128);

  // x0 projection
  proj_kernel<<<N_NODES / 16, 256, 0, stream>>>(x, Wm, bm, Wc, bc, x0);

  // GCN layers: fp32 gemm + CSR gather
  dim3 grid2(313, 2), grid4(313, 4);
  gcn_gemm_kernel<64, 128><<<grid2, 256, 0, stream>>>(x0, Wg1, bg1, dinv, hbuf, gA, N_NODES);
  gcn_gather_kernel<128><<<N_NODES * 128 / 256, 256, 0, stream>>>(hbuf, row_ptr, ssrc, dinv,
                                                                  gA, N_NODES);
  gcn_gemm_kernel<128, 128><<<grid2, 256, 0, stream>>>(gA, Wg2, bg2, dinv, hbuf, gB, N_NODES);
  gcn_gather_kernel<128><<<N_NODES * 128 / 256, 256, 0, stream>>>(hbuf, row_ptr, ssrc, dinv,
                                                                  gB, N_NODES);
  gcn_gemm_kernel<128, 256><<<grid4, 256, 0, stream>>>(gB, Wg3, bg3, dinv, hbuf, gA, N_NODES);
  gcn_gather_kernel<256><<<N_NODES * 256 / 256, 256, 0, stream>>>(hbuf, row_ptr, ssrc, dinv,
                                                                  gA, N_NODES);

  const int NODE_BLOCKS = (N_NODES + 127) / 128;  // 157
  const int EDGE_BLOCKS = N_EDGES / 128;          // 2500
  const int NB_ELEM     = N_NODES * 128 / 256;

  // EdgeConv 1: gA [N,256] -> gB [N,128]
  hipMemsetAsync(Qbuf, 0, (size_t)N_NODES * 128 * 4, stream);
  ec_mfma_kernel<256, false><<<NODE_BLOCKS, 256, 0, stream>>>(
      gA, nullptr, nullptr, sc1, sh1, bf1p, nullptr, Pbuf, N_NODES);
  ec_mfma_kernel<256, true><<<EDGE_BLOCKS, 256, 0, stream>>>(
      gA, ssrc, sdst, sc1 + 256, sh1 + 256, bf1q, Qbuf, nullptr, N_NODES);
  combine_kernel<<<NB_ELEM, 256, 0, stream>>>(Qbuf, Pbuf, gB, N_NODES * 128);

  // EdgeConv 2: gB [N,128] -> gA [N,128]
  hipMemsetAsync(Qbuf, 0, (size_t)N_NODES * 128 * 4, stream);
  ec_mfma_kernel<128, false><<<NODE_BLOCKS, 256, 0, stream>>>(
      gB, nullptr, nullptr, sc2, sh2, bf2p, nullptr, Pbuf, N_NODES);
  ec_mfma_kernel<128, true><<<EDGE_BLOCKS, 256, 0, stream>>>(
      gB, ssrc, sdst, sc2 + 128, sh2 + 128, bf2q, Qbuf, nullptr, N_NODES);
  combine_kernel<<<NB_ELEM, 256, 0, stream>>>(Qbuf, Pbuf, gA, N_NODES * 128);

  // EdgeConv 3: gA [N,128] -> gB [N,128]
  hipMemsetAsync(Qbuf, 0, (size_t)N_NODES * 128 * 4, stream);
  ec_mfma_kernel<128, false><<<NODE_BLOCKS, 256, 0, stream>>>(
      gA, nullptr, nullptr, sc3, sh3, bf3p, nullptr, Pbuf, N_NODES);
  ec_mfma_kernel<128, true><<<EDGE_BLOCKS, 256, 0, stream>>>(
      gA, ssrc, sdst, sc3 + 128, sh3 + 128, bf3q, Qbuf, nullptr, N_NODES);
  combine_kernel<<<NB_ELEM, 256, 0, stream>>>(Qbuf, Pbuf, gB, N_NODES * 128);

  // final FC
  fc_kernel<<<N_NODES * 64 / 256, 256, 0, stream>>>(gB, Wfc, bfc, (float*)d_out, N_NODES);
}

// Round 5
// 821.223 us; speedup vs baseline: 4.4931x; 1.3195x over previous
//
#include <hip/hip_runtime.h>

#define DEVINL __device__ __forceinline__

constexpr int N_NODES  = 20000;
constexpr int N_EDGES  = 320000;
constexpr int IN_FEATS = 512;

static_assert(N_EDGES % 128 == 0, "edge tiling assumes E % 128 == 0");
static_assert(N_NODES % 16 == 0, "proj assumes N % 16 == 0");

typedef __attribute__((ext_vector_type(8))) short short8;  // 8 bf16 = 4 VGPR
typedef __attribute__((ext_vector_type(4))) float f32x4;   // MFMA acc

// ---- monotone float<->uint order encoding (for atomicMax-based segment_max) ----
DEVINL unsigned enc_f32(float v) {
  unsigned b = __float_as_uint(v);
  return (b & 0x80000000u) ? ~b : (b | 0x80000000u);
}
DEVINL float dec_f32(unsigned e) {
  unsigned b = (e & 0x80000000u) ? (e & 0x7FFFFFFFu) : ~e;
  return __uint_as_float(b);
}

// ---- bf16 split helpers (A = hi + lo, each RNE bf16) ----
DEVINL unsigned short bf16_rne(float f) {
  unsigned u = __float_as_uint(f);
  u += 0x7FFFu + ((u >> 16) & 1u);
  return (unsigned short)(u >> 16);
}
DEVINL void split_bf16(float v, unsigned short& h, unsigned short& l) {
  h = bf16_rne(v);
  float hf = __uint_as_float((unsigned)h << 16);
  l = bf16_rne(v - hf);
}

// ---- async global->LDS (16B per lane, wave-uniform LDS base) ----
DEVINL void glds16(const unsigned short* g, unsigned short* l) {
  __builtin_amdgcn_global_load_lds(
      (const __attribute__((address_space(1))) unsigned int*)g,
      (__attribute__((address_space(3))) unsigned int*)l, 16, 0, 0);
}

// ---------------- CSR build (counting sort by dst) ----------------
__global__ void hist_kernel(const int* __restrict__ dst, int* __restrict__ cnt, int e) {
  int i = blockIdx.x * 256 + threadIdx.x;
  if (i < e) atomicAdd(&cnt[dst[i]], 1);
}
__global__ void dinv_kernel(const int* __restrict__ cnt, float* __restrict__ dinv, int n) {
  int i = blockIdx.x * 256 + threadIdx.x;
  if (i < n) dinv[i] = rsqrtf((float)cnt[i] + 1.0f);  // +1 self-loop
}
// 3-phase multi-block exclusive scan (old single-block scan was ~50us serial)
__global__ void __launch_bounds__(256)
scan_p1(const int* __restrict__ cnt, int* __restrict__ rp, int* __restrict__ bsum, int n) {
  __shared__ int buf[256];
  int i = blockIdx.x * 256 + threadIdx.x;
  int v = (i < n) ? cnt[i] : 0;
  buf[threadIdx.x] = v;
  __syncthreads();
  for (int off = 1; off < 256; off <<= 1) {
    int t = (threadIdx.x >= off) ? buf[threadIdx.x - off] : 0;
    __syncthreads();
    buf[threadIdx.x] += t;
    __syncthreads();
  }
  if (i < n) rp[i] = buf[threadIdx.x] - v;
  if (threadIdx.x == 255) bsum[blockIdx.x] = buf[255];
}
__global__ void __launch_bounds__(256)
scan_p2(int* __restrict__ bsum, int nb) {
  __shared__ int buf[256];
  int v = (threadIdx.x < nb) ? bsum[threadIdx.x] : 0;
  buf[threadIdx.x] = v;
  __syncthreads();
  for (int off = 1; off < 256; off <<= 1) {
    int t = (threadIdx.x >= off) ? buf[threadIdx.x - off] : 0;
    __syncthreads();
    buf[threadIdx.x] += t;
    __syncthreads();
  }
  if (threadIdx.x < nb) bsum[threadIdx.x] = buf[threadIdx.x] - v;  // exclusive
}
__global__ void __launch_bounds__(256)
scan_p3(int* __restrict__ rp, const int* __restrict__ bsum, int* __restrict__ cursor,
        int n, int e) {
  int i = blockIdx.x * 256 + threadIdx.x;
  if (i < n) {
    int v = rp[i] + bsum[blockIdx.x];
    rp[i] = v;
    cursor[i] = v;
  }
  if (i == 0) rp[n] = e;
}
__global__ void scatter_edges_kernel(const int* __restrict__ src, const int* __restrict__ dst,
                                     int* __restrict__ cursor, int* __restrict__ ssrc,
                                     int* __restrict__ sdst, int e) {
  int i = blockIdx.x * 256 + threadIdx.x;
  if (i < e) {
    int d = dst[i];
    int pos = atomicAdd(&cursor[d], 1);
    ssrc[pos] = src[i];
    sdst[pos] = d;
  }
}

// ---------------- merged small setup kernels ----------------
DEVINL void bn1(const float* g, const float* b, const float* m, const float* v,
                float* sc, float* sh, int i) {
  float s = g[i] * rsqrtf(v[i] + 1e-5f);
  sc[i] = s;
  sh[i] = b[i] - m[i] * s;
}
__global__ void bn_prep_all(const float* g1, const float* b1, const float* m1, const float* v1,
                            float* sc1, float* sh1, const float* g2, const float* b2,
                            const float* m2, const float* v2, float* sc2, float* sh2,
                            const float* g3, const float* b3, const float* m3, const float* v3,
                            float* sc3, float* sh3) {
  int i = blockIdx.x * 256 + threadIdx.x;  // 1024 total
  if (i < 512) bn1(g1, b1, m1, v1, sc1, sh1, i);
  else if (i < 768) bn1(g2, b2, m2, v2, sc2, sh2, i - 512);
  else if (i < 1024) bn1(g3, b3, m3, v3, sc3, sh3, i - 768);
}

// W pre-transform into frag image (split bf16 hi/lo).  Per 32-k chunk (16 KB):
// hi 8 KB then lo 8 KB; frag = (ct*4+kq)*16+n (ct=c>>4, kq=(k>>3)&3, n=c&15), j=k&7.
DEVINL void wfrag1(const float* W, unsigned short* out, int e) {
  int k = e >> 7, c = e & 127;
  unsigned short h, l;
  split_bf16(W[e], h, l);
  int chunk = k >> 5, kq = (k >> 3) & 3, j = k & 7, ct = c >> 4, n = c & 15;
  int frag = (ct * 4 + kq) * 16 + n;
  size_t o = (size_t)chunk * 8192 + frag * 8 + j;
  out[o] = h;
  out[o + 4096] = l;
}
__global__ void wfrag_all(const float* __restrict__ e1W, const float* __restrict__ e2W,
                          const float* __restrict__ e3W, unsigned short* b1p,
                          unsigned short* b1q, unsigned short* b2p, unsigned short* b2q,
                          unsigned short* b3p, unsigned short* b3q) {
  int g = blockIdx.x * 256 + threadIdx.x;  // 131072 total
  if (g < 32768) wfrag1(e1W, b1p, g);
  else if (g < 65536) wfrag1(e1W + 32768, b1q, g - 32768);
  else if (g < 81920) wfrag1(e2W, b2p, g - 65536);
  else if (g < 98304) wfrag1(e2W + 16384, b2q, g - 81920);
  else if (g < 114688) wfrag1(e3W, b3p, g - 98304);
  else wfrag1(e3W + 16384, b3q, g - 114688);
}

// combine: H = Q written ? P + dec(Q) : 0 ; optionally re-zero Q for next layer
__global__ void combine_kernel(unsigned* __restrict__ Q, const float* __restrict__ P,
                               float* __restrict__ H, int n, int zq) {
  int i = blockIdx.x * 256 + threadIdx.x;
  if (i < n) {
    unsigned e = Q[i];
    H[i] = e ? (P[i] + dec_f32(e)) : 0.f;
    if (zq) Q[i] = 0u;
  }
}

// ---------------- input projection: rows 0 mod 4 use Wm/bm, else Wc/bc ----------------
// writes Y0 = (x@W + b) * dinv[row]  (pre-scaled for the aggregate)
__global__ void __launch_bounds__(256)
proj_kernel(const float* __restrict__ X, const float* __restrict__ Wm,
            const float* __restrict__ bm, const float* __restrict__ Wc,
            const float* __restrict__ bc, const float* __restrict__ dinv,
            float* __restrict__ Y0) {
  __shared__ float xs[16][IN_FEATS];  // 32 KB
  int tid = threadIdx.x;
  int rowBase = blockIdx.x * 16;
  for (int i = 0; i < 8; ++i) {
    int idx = i * 256 + tid;
    int r = idx >> 7, kq = idx & 127;
    *reinterpret_cast<float4*>(&xs[r][kq * 4]) =
        *reinterpret_cast<const float4*>(X + (size_t)(rowBase + r) * IN_FEATS + kq * 4);
  }
  __syncthreads();
  int r4 = tid >> 6;  // residue class (wave-uniform); wave0 -> Wm, else Wc
  int j = tid & 63;
  const float* W = (r4 == 0) ? Wm : Wc;
  float a0 = 0.f, a1 = 0.f, a2 = 0.f, a3 = 0.f;
#pragma unroll 4
  for (int k = 0; k < IN_FEATS; ++k) {
    float w = W[k * 64 + j];
    a0 = fmaf(xs[r4][k], w, a0);
    a1 = fmaf(xs[r4 + 4][k], w, a1);
    a2 = fmaf(xs[r4 + 8][k], w, a2);
    a3 = fmaf(xs[r4 + 12][k], w, a3);
  }
  float b = (r4 == 0) ? bm[j] : bc[j];
  int r0 = rowBase + r4;
  Y0[(size_t)r0 * 64 + j] = (a0 + b) * dinv[r0];
  Y0[(size_t)(r0 + 4) * 64 + j] = (a1 + b) * dinv[r0 + 4];
  Y0[(size_t)(r0 + 8) * 64 + j] = (a2 + b) * dinv[r0 + 8];
  Y0[(size_t)(r0 + 12) * 64 + j] = (a3 + b) * dinv[r0 + 12];
}

// ------- GCN aggregate (CSR gather, float4): Z_d = dinv_d * (Y_d + sum Y_src) -------
template <int LOGF4>
__global__ void __launch_bounds__(256)
agg_kernel(const float* __restrict__ Y, const int* __restrict__ row_ptr,
           const int* __restrict__ ssrc, const float* __restrict__ dinv,
           float* __restrict__ Z, int n) {
  constexpr int F4 = 1 << LOGF4;
  int g = blockIdx.x * 256 + threadIdx.x;
  int d = g >> LOGF4, c4 = g & (F4 - 1);
  if (d >= n) return;
  const float4* Yp = (const float4*)Y;
  float4 a = Yp[(size_t)d * F4 + c4];  // self term (Y already *dinv)
  float ax = a.x, ay = a.y, az = a.z, aw = a.w;
  int e = row_ptr[d], end = row_ptr[d + 1];
  for (; e + 1 < end; e += 2) {
    int s0 = ssrc[e], s1 = ssrc[e + 1];
    float4 v0 = Yp[(size_t)s0 * F4 + c4];
    float4 v1 = Yp[(size_t)s1 * F4 + c4];
    ax += v0.x + v1.x; ay += v0.y + v1.y; az += v0.z + v1.z; aw += v0.w + v1.w;
  }
  if (e < end) {
    float4 v = Yp[(size_t)ssrc[e] * F4 + c4];
    ax += v.x; ay += v.y; az += v.z; aw += v.w;
  }
  float s = dinv[d];
  ((float4*)Z)[(size_t)d * F4 + c4] = make_float4(ax * s, ay * s, az * s, aw * s);
}

// ------- GCN dense: H = Z@W + b  (optionally * dinv[row] for the next aggregate) -------
template <int K, int F, bool SCALE>
__global__ void __launch_bounds__(256)
gemm_kernel(const float* __restrict__ X, const float* __restrict__ W,
            const float* __restrict__ bias, const float* __restrict__ dinv,
            float* __restrict__ H, int n) {
  __shared__ float Xs[64][K + 1];
  __shared__ float Ws[K][65];
  int tid = threadIdx.x;
  int rowBase = blockIdx.x * 64;
  int colBase = blockIdx.y * 64;
  for (int idx = tid; idx < 64 * K; idx += 256) {
    int r = idx / K, k = idx % K;
    int row = rowBase + r;
    Xs[r][k] = (row < n) ? X[(size_t)row * K + k] : 0.f;
  }
  for (int idx = tid; idx < K * 64; idx += 256) {
    int k = idx >> 6, c = idx & 63;
    Ws[k][c] = W[(size_t)k * F + colBase + c];
  }
  __syncthreads();
  int tx = tid & 15, ty = tid >> 4;
  float acc[4][4] = {};
  for (int k = 0; k < K; ++k) {
    float a[4], b[4];
#pragma unroll
    for (int r = 0; r < 4; ++r) a[r] = Xs[ty * 4 + r][k];
#pragma unroll
    for (int c = 0; c < 4; ++c) b[c] = Ws[k][tx * 4 + c];
#pragma unroll
    for (int r = 0; r < 4; ++r)
#pragma unroll
      for (int c = 0; c < 4; ++c) acc[r][c] = fmaf(a[r], b[c], acc[r][c]);
  }
#pragma unroll
  for (int r = 0; r < 4; ++r) {
    int row = rowBase + ty * 4 + r;
    if (row < n) {
      float di = SCALE ? dinv[row] : 1.0f;
#pragma unroll
      for (int c = 0; c < 4; ++c) {
        int col = colBase + tx * 4 + c;
        float v = acc[r][c] + bias[col];
        H[(size_t)row * F + col] = SCALE ? v * di : v;
      }
    }
  }
}

// ---------------- EdgeConv split-bf16 MFMA GEMM, v5 (pipelined, no LDS-A) ----------------
// 128 rows x 128 cols per block, 4 waves; wave w owns rows [w*32, w*32+32).
// A-frag (A[m=lane&15][k=q*8+j]) = 8 consecutive floats of one row -> direct
// global->reg load, BN+ReLU+split in-reg; prefetched one chunk ahead.
// B double-buffered in LDS via global_load_lds (issued after the single
// per-chunk barrier so the barrier's vmcnt drain never waits on fresh loads).
DEVINL void proc8(const float4& va, const float4& vb, const float4& sa, const float4& sb,
                  const float4& ha, const float4& hb, short8& hi, short8& lo) {
  float f[8] = {va.x, va.y, va.z, va.w, vb.x, vb.y, vb.z, vb.w};
  float s[8] = {sa.x, sa.y, sa.z, sa.w, sb.x, sb.y, sb.z, sb.w};
  float t[8] = {ha.x, ha.y, ha.z, ha.w, hb.x, hb.y, hb.z, hb.w};
#pragma unroll
  for (int j = 0; j < 8; ++j) {
    float v = fmaxf(fmaf(f[j], s[j], t[j]), 0.f);
    unsigned short hh, ll;
    split_bf16(v, hh, ll);
    hi[j] = (short)hh;
    lo[j] = (short)ll;
  }
}

template <int C, bool EDGE>
__global__ void __launch_bounds__(256, 3)
ec_mfma_kernel(const float* __restrict__ X, const int* __restrict__ ssrc,
               const int* __restrict__ sdst, const float* __restrict__ scale,
               const float* __restrict__ shift, const unsigned short* __restrict__ Bfrag,
               unsigned* __restrict__ outU, float* __restrict__ outP, int nrows) {
  constexpr int NCH = C / 32;
  __shared__ unsigned short Bb[2][8192];  // 2 x 16 KB (hi 8 KB + lo 8 KB per chunk)
  __shared__ int de_s[128];
  const int tid = threadIdx.x, lane = tid & 63, wv = tid >> 6;
  const int q = lane >> 4, mn = lane & 15;
  const int base = blockIdx.x * 128;
  const int koff = q * 8;
  const int lr0 = wv * 32 + mn, lr1 = lr0 + 16;  // local rows this lane loads A for

  int id0, id1, is0 = 0, is1 = 0;
  if (EDGE) {
    if (tid < 128) de_s[tid] = sdst[base + tid];
    is0 = ssrc[base + lr0];
    id0 = sdst[base + lr0];
    is1 = ssrc[base + lr1];
    id1 = sdst[base + lr1];
  } else {
    id0 = min(base + lr0, nrows - 1);
    id1 = min(base + lr1, nrows - 1);
  }
  const float* pd0 = X + (size_t)id0 * C + koff;
  const float* pd1 = X + (size_t)id1 * C + koff;
  const float* ps0 = EDGE ? X + (size_t)is0 * C + koff : nullptr;
  const float* ps1 = EDGE ? X + (size_t)is1 * C + koff : nullptr;

  f32x4 acc[8][2];
#pragma unroll
  for (int i = 0; i < 8; ++i) {
    acc[i][0] = (f32x4)0.f;
    acc[i][1] = (f32x4)0.f;
  }

  // prologue: A(0) into regs first (so vmcnt wait for A doesn't drain B), then B(0)
  float4 pa0, pa1, pa2, pa3, pb0, pb1, pb2, pb3;
  pa0 = *(const float4*)(pd0);
  pa1 = *(const float4*)(pd0 + 4);
  pa2 = *(const float4*)(pd1);
  pa3 = *(const float4*)(pd1 + 4);
  if (EDGE) {
    pb0 = *(const float4*)(ps0);
    pb1 = *(const float4*)(ps0 + 4);
    pb2 = *(const float4*)(ps1);
    pb3 = *(const float4*)(ps1 + 4);
  }
  {
    const unsigned short* bs = Bfrag + lane * 8;
#pragma unroll
    for (int i = 0; i < 4; ++i) {
      int seg = i * 4 + wv;
      glds16(bs + seg * 512, &Bb[0][seg * 512]);
    }
  }

  for (int c = 0; c < NCH; ++c) {
    const int kc = c * 32;
    float4 sca = *(const float4*)(scale + kc + koff);
    float4 scb = *(const float4*)(scale + kc + koff + 4);
    float4 sha = *(const float4*)(shift + kc + koff);
    float4 shb = *(const float4*)(shift + kc + koff + 4);
    float4 u0, u1, u2, u3;
    if (EDGE) {
      u0 = make_float4(pb0.x - pa0.x, pb0.y - pa0.y, pb0.z - pa0.z, pb0.w - pa0.w);
      u1 = make_float4(pb1.x - pa1.x, pb1.y - pa1.y, pb1.z - pa1.z, pb1.w - pa1.w);
      u2 = make_float4(pb2.x - pa2.x, pb2.y - pa2.y, pb2.z - pa2.z, pb2.w - pa2.w);
      u3 = make_float4(pb3.x - pa3.x, pb3.y - pa3.y, pb3.z - pa3.z, pb3.w - pa3.w);
    } else {
      u0 = pa0; u1 = pa1; u2 = pa2; u3 = pa3;
    }
    short8 ah0, al0, ah1, al1;
    proc8(u0, u1, sca, scb, sha, shb, ah0, al0);
    proc8(u2, u3, sca, scb, sha, shb, ah1, al1);
    __syncthreads();  // B(c) DMA drained here; buf[(c+1)&1] free (prev compute done)
    if (c + 1 < NCH) {
      const int k2 = kc + 32;
      pa0 = *(const float4*)(pd0 + k2);
      pa1 = *(const float4*)(pd0 + k2 + 4);
      pa2 = *(const float4*)(pd1 + k2);
      pa3 = *(const float4*)(pd1 + k2 + 4);
      if (EDGE) {
        pb0 = *(const float4*)(ps0 + k2);
        pb1 = *(const float4*)(ps0 + k2 + 4);
        pb2 = *(const float4*)(ps1 + k2);
        pb3 = *(const float4*)(ps1 + k2 + 4);
      }
      const unsigned short* bs = Bfrag + (size_t)(c + 1) * 8192 + lane * 8;
      unsigned short* bd = Bb[(c + 1) & 1];
#pragma unroll
      for (int i = 0; i < 4; ++i) {
        int seg = i * 4 + wv;
        glds16(bs + seg * 512, bd + seg * 512);
      }
    }
    const unsigned short* Bc = Bb[c & 1];
#pragma unroll
    for (int ct = 0; ct < 8; ++ct) {
      int fi = ct * 64 + lane;
      short8 bh = *(const short8*)(Bc + fi * 8);
      short8 bl = *(const short8*)(Bc + 4096 + fi * 8);
      acc[ct][0] = __builtin_amdgcn_mfma_f32_16x16x32_bf16(ah0, bh, acc[ct][0], 0, 0, 0);
      acc[ct][1] = __builtin_amdgcn_mfma_f32_16x16x32_bf16(ah1, bh, acc[ct][1], 0, 0, 0);
      acc[ct][0] = __builtin_amdgcn_mfma_f32_16x16x32_bf16(ah0, bl, acc[ct][0], 0, 0, 0);
      acc[ct][1] = __builtin_amdgcn_mfma_f32_16x16x32_bf16(ah1, bl, acc[ct][1], 0, 0, 0);
      acc[ct][0] = __builtin_amdgcn_mfma_f32_16x16x32_bf16(al0, bh, acc[ct][0], 0, 0, 0);
      acc[ct][1] = __builtin_amdgcn_mfma_f32_16x16x32_bf16(al1, bh, acc[ct][1], 0, 0, 0);
    }
  }

  // ---- epilogue: C/D layout col=lane&15, row=q*4+reg; rows dst-sorted -> run-merge ----
  if (EDGE) {
#pragma unroll
    for (int ct = 0; ct < 8; ++ct) {
      int f = ct * 16 + mn;
      float mv = 0.f;
      int prev = -1;
#pragma unroll
      for (int g = 0; g < 2; ++g) {
        int e0 = wv * 32 + g * 16 + q * 4;
#pragma unroll
        for (int r = 0; r < 4; ++r) {
          int d = de_s[e0 + r];
          float v = acc[ct][g][r];
          if (prev < 0) {
            prev = d; mv = v;
          } else if (d == prev) {
            mv = fmaxf(mv, v);
          } else {
            atomicMax(&outU[(size_t)prev * 128 + f], enc_f32(mv));
            prev = d; mv = v;
          }
        }
      }
      atomicMax(&outU[(size_t)prev * 128 + f], enc_f32(mv));
    }
  } else {
#pragma unroll
    for (int ct = 0; ct < 8; ++ct) {
      int f = ct * 16 + mn;
#pragma unroll
      for (int g = 0; g < 2; ++g) {
        int r0 = base + wv * 32 + g * 16 + q * 4;
#pragma unroll
        for (int r = 0; r < 4; ++r) {
          int row = r0 + r;
          if (row < nrows) outP[(size_t)row * 128 + f] = acc[ct][g][r];
        }
      }
    }
  }
}

// ---------------- final FC: out[i] = h[i,0:128] . Wfc + bfc ----------------
__global__ void __launch_bounds__(256)
fc_kernel(const float* __restrict__ Hf, const float* __restrict__ Wfc,
          const float* __restrict__ bfc, float* __restrict__ out, int n) {
  int g = blockIdx.x * 256 + threadIdx.x;
  int node = g >> 6, lane = g & 63;
  if (node >= n) return;
  float v = fmaf(Hf[(size_t)node * 128 + lane], Wfc[lane],
                 Hf[(size_t)node * 128 + 64 + lane] * Wfc[64 + lane]);
#pragma unroll
  for (int off = 32; off > 0; off >>= 1) v += __shfl_down(v, off);
  if (lane == 0) out[node] = v + bfc[0];
}

extern "C" void kernel_launch(void* const* d_in, const int* in_sizes, int n_in,
                              void* d_out, int out_size, void* d_ws, size_t ws_size,
                              hipStream_t stream) {
  const float* x   = (const float*)d_in[0];
  const int*   ei  = (const int*)d_in[1];
  const float* Wm  = (const float*)d_in[2];
  const float* bm  = (const float*)d_in[3];
  const float* Wc  = (const float*)d_in[4];
  const float* bc  = (const float*)d_in[5];
  const float* Wg1 = (const float*)d_in[6];
  const float* bg1 = (const float*)d_in[7];
  const float* Wg2 = (const float*)d_in[8];
  const float* bg2 = (const float*)d_in[9];
  const float* Wg3 = (const float*)d_in[10];
  const float* bg3 = (const float*)d_in[11];
  const float* e1g = (const float*)d_in[12];
  const float* e1b = (const float*)d_in[13];
  const float* e1m = (const float*)d_in[14];
  const float* e1v = (const float*)d_in[15];
  const float* e1W = (const float*)d_in[16];
  const float* e2g = (const float*)d_in[17];
  const float* e2b = (const float*)d_in[18];
  const float* e2m = (const float*)d_in[19];
  const float* e2v = (const float*)d_in[20];
  const float* e2W = (const float*)d_in[21];
  const float* e3g = (const float*)d_in[22];
  const float* e3b = (const float*)d_in[23];
  const float* e3m = (const float*)d_in[24];
  const float* e3v = (const float*)d_in[25];
  const float* e3W = (const float*)d_in[26];
  const float* Wfc = (const float*)d_in[27];
  const float* bfc = (const float*)d_in[28];

  const int* src = ei;
  const int* dst = ei + N_EDGES;

  // ---- workspace layout (floats), ~50 MB ----
  float* ws   = (float*)d_ws;
  float* dinv = ws;                                   // N
  float* y0   = dinv + N_NODES;                       // N*64
  float* zb   = y0 + (size_t)N_NODES * 64;            // N*128 (Z, later P)
  float* yb   = zb + (size_t)N_NODES * 128;           // N*128 (Y1/Y2, later Q)
  float* G    = yb + (size_t)N_NODES * 128;           // N*256 (G; H1@base, H2@+N*128, H3@base)
  float* sc1  = G + (size_t)N_NODES * 256;            // 512
  float* sh1  = sc1 + 512;
  float* sc2  = sh1 + 512;                            // 256
  float* sh2  = sc2 + 256;
  float* sc3  = sh2 + 256;
  float* sh3  = sc3 + 256;
  unsigned short* bf1p = (unsigned short*)(sh3 + 256);  // frag images, 512 KB total
  unsigned short* bf1q = bf1p + 65536;
  unsigned short* bf2p = bf1q + 65536;
  unsigned short* bf2q = bf2p + 32768;
  unsigned short* bf3p = bf2q + 32768;
  unsigned short* bf3q = bf3p + 32768;
  int* cnt     = (int*)(bf3q + 32768);                // N
  int* row_ptr = cnt + N_NODES;                       // N+1
  int* cursor  = row_ptr + N_NODES + 1;               // N
  int* bsum    = cursor + N_NODES;                    // 256
  int* ssrc    = bsum + 256;                          // E
  int* sdst    = ssrc + N_EDGES;                      // E

  float*    Pbuf = zb;
  unsigned* Qbuf = (unsigned*)yb;

  // ---- CSR build (counting sort by dst) + dinv ----
  hipMemsetAsync(cnt, 0, N_NODES * sizeof(int), stream);
  hist_kernel<<<N_EDGES / 256, 256, 0, stream>>>(dst, cnt, N_EDGES);
  dinv_kernel<<<79, 256, 0, stream>>>(cnt, dinv, N_NODES);
  scan_p1<<<79, 256, 0, stream>>>(cnt, row_ptr, bsum, N_NODES);
  scan_p2<<<1, 256, 0, stream>>>(bsum, 79);
  scan_p3<<<79, 256, 0, stream>>>(row_ptr, bsum, cursor, N_NODES, N_EDGES);
  scatter_edges_kernel<<<N_EDGES / 256, 256, 0, stream>>>(src, dst, cursor, ssrc, sdst,
                                                          N_EDGES);

  // ---- BN fold + W frag pre-transforms (merged) ----
  bn_prep_all<<<4, 256, 0, stream>>>(e1g, e1b, e1m, e1v, sc1, sh1, e2g, e2b, e2m, e2v, sc2,
                                     sh2, e3g, e3b, e3m, e3v, sc3, sh3);
  wfrag_all<<<512, 256, 0, stream>>>(e1W, e2W, e3W, bf1p, bf1q, bf2p, bf2q, bf3p, bf3q);

  // ---- GCN: aggregate-first reassociation  H = (A~ X) W + b ----
  proj_kernel<<<N_NODES / 16, 256, 0, stream>>>(x, Wm, bm, Wc, bc, dinv, y0);
  dim3 grid2(313, 2), grid4(313, 4);
  agg_kernel<4><<<N_NODES * 16 / 256, 256, 0, stream>>>(y0, row_ptr, ssrc, dinv, zb, N_NODES);
  gemm_kernel<64, 128, true><<<grid2, 256, 0, stream>>>(zb, Wg1, bg1, dinv, yb, N_NODES);
  agg_kernel<5><<<N_NODES * 32 / 256, 256, 0, stream>>>(yb, row_ptr, ssrc, dinv, zb, N_NODES);
  gemm_kernel<128, 128, true><<<grid2, 256, 0, stream>>>(zb, Wg2, bg2, dinv, yb, N_NODES);
  agg_kernel<5><<<N_NODES * 32 / 256, 256, 0, stream>>>(yb, row_ptr, ssrc, dinv, zb, N_NODES);
  gemm_kernel<128, 256, false><<<grid4, 256, 0, stream>>>(zb, Wg3, bg3, dinv, G, N_NODES);

  const int NODE_BLOCKS = (N_NODES + 127) / 128;  // 157
  const int EDGE_BLOCKS = N_EDGES / 128;          // 2500
  const int NB_ELEM     = N_NODES * 128 / 256;    // 10000

  float* H1 = G;                        // combine1 -> G base (G dead after EC1)
  float* H2 = G + (size_t)N_NODES * 128;
  float* H3 = G;

  // EdgeConv 1: G [N,256] -> H1 [N,128]
  hipMemsetAsync(Qbuf, 0, (size_t)N_NODES * 128 * 4, stream);
  ec_mfma_kernel<256, false><<<NODE_BLOCKS, 256, 0, stream>>>(
      G, nullptr, nullptr, sc1, sh1, bf1p, nullptr, Pbuf, N_NODES);
  ec_mfma_kernel<256, true><<<EDGE_BLOCKS, 256, 0, stream>>>(
      G, ssrc, sdst, sc1 + 256, sh1 + 256, bf1q, Qbuf, nullptr, N_NODES);
  combine_kernel<<<NB_ELEM, 256, 0, stream>>>(Qbuf, Pbuf, H1, N_NODES * 128, 1);

  // EdgeConv 2: H1 -> H2
  ec_mfma_kernel<128, false><<<NODE_BLOCKS, 256, 0, stream>>>(
      H1, nullptr, nullptr, sc2, sh2, bf2p, nullptr, Pbuf, N_NODES);
  ec_mfma_kernel<128, true><<<EDGE_BLOCKS, 256, 0, stream>>>(
      H1, ssrc, sdst, sc2 + 128, sh2 + 128, bf2q, Qbuf, nullptr, N_NODES);
  combine_kernel<<<NB_ELEM, 256, 0, stream>>>(Qbuf, Pbuf, H2, N_NODES * 128, 1);

  // EdgeConv 3: H2 -> H3 (over H1, dead)
  ec_mfma_kernel<128, false><<<NODE_BLOCKS, 256, 0, stream>>>(
      H2, nullptr, nullptr, sc3, sh3, bf3p, nullptr, Pbuf, N_NODES);
  ec_mfma_kernel<128, true><<<EDGE_BLOCKS, 256, 0, stream>>>(
      H2, ssrc, sdst, sc3 + 128, sh3 + 128, bf3q, Qbuf, nullptr, N_NODES);
  combine_kernel<<<NB_ELEM, 256, 0, stream>>>(Qbuf, Pbuf, H3, N_NODES * 128, 0);

  // final FC
  fc_kernel<<<N_NODES * 64 / 256, 256, 0, stream>>>(H3, Wfc, bfc, (float*)d_out, N_NODES);
}

// Round 6
// 819.597 us; speedup vs baseline: 4.5021x; 1.0020x over previous
//
#include <hip/hip_runtime.h>

#define DEVINL __device__ __forceinline__

constexpr int N_NODES  = 20000;
constexpr int N_EDGES  = 320000;
constexpr int IN_FEATS = 512;

static_assert(N_EDGES % 128 == 0, "edge tiling assumes E % 128 == 0");
static_assert(N_NODES % 16 == 0, "proj assumes N % 16 == 0");

typedef __attribute__((ext_vector_type(8))) short short8;  // 8 bf16 = 4 VGPR
typedef __attribute__((ext_vector_type(4))) float f32x4;   // MFMA acc

// ---- monotone float<->uint order encoding (for atomicMax-based segment_max) ----
DEVINL unsigned enc_f32(float v) {
  unsigned b = __float_as_uint(v);
  return (b & 0x80000000u) ? ~b : (b | 0x80000000u);
}
DEVINL float dec_f32(unsigned e) {
  unsigned b = (e & 0x80000000u) ? (e & 0x7FFFFFFFu) : ~e;
  return __uint_as_float(b);
}

// ---- bf16 split helpers (A = hi + lo, each RNE bf16) ----
DEVINL unsigned short bf16_rne(float f) {
  unsigned u = __float_as_uint(f);
  u += 0x7FFFu + ((u >> 16) & 1u);
  return (unsigned short)(u >> 16);
}
DEVINL void split_bf16(float v, unsigned short& h, unsigned short& l) {
  h = bf16_rne(v);
  float hf = __uint_as_float((unsigned)h << 16);
  l = bf16_rne(v - hf);
}

// ---- async global->LDS (16B per lane, wave-uniform LDS base) ----
DEVINL void glds16(const unsigned short* g, unsigned short* l) {
  __builtin_amdgcn_global_load_lds(
      (const __attribute__((address_space(1))) unsigned int*)g,
      (__attribute__((address_space(3))) unsigned int*)l, 16, 0, 0);
}

// ---------------- CSR build (counting sort by dst) ----------------
__global__ void hist_kernel(const int* __restrict__ dst, int* __restrict__ cnt, int e) {
  int i = blockIdx.x * 256 + threadIdx.x;
  if (i < e) atomicAdd(&cnt[dst[i]], 1);
}
__global__ void dinv_kernel(const int* __restrict__ cnt, float* __restrict__ dinv, int n) {
  int i = blockIdx.x * 256 + threadIdx.x;
  if (i < n) dinv[i] = rsqrtf((float)cnt[i] + 1.0f);  // +1 self-loop
}
// 3-phase multi-block exclusive scan
__global__ void __launch_bounds__(256)
scan_p1(const int* __restrict__ cnt, int* __restrict__ rp, int* __restrict__ bsum, int n) {
  __shared__ int buf[256];
  int i = blockIdx.x * 256 + threadIdx.x;
  int v = (i < n) ? cnt[i] : 0;
  buf[threadIdx.x] = v;
  __syncthreads();
  for (int off = 1; off < 256; off <<= 1) {
    int t = (threadIdx.x >= off) ? buf[threadIdx.x - off] : 0;
    __syncthreads();
    buf[threadIdx.x] += t;
    __syncthreads();
  }
  if (i < n) rp[i] = buf[threadIdx.x] - v;
  if (threadIdx.x == 255) bsum[blockIdx.x] = buf[255];
}
__global__ void __launch_bounds__(256)
scan_p2(int* __restrict__ bsum, int nb) {
  __shared__ int buf[256];
  int v = (threadIdx.x < nb) ? bsum[threadIdx.x] : 0;
  buf[threadIdx.x] = v;
  __syncthreads();
  for (int off = 1; off < 256; off <<= 1) {
    int t = (threadIdx.x >= off) ? buf[threadIdx.x - off] : 0;
    __syncthreads();
    buf[threadIdx.x] += t;
    __syncthreads();
  }
  if (threadIdx.x < nb) bsum[threadIdx.x] = buf[threadIdx.x] - v;  // exclusive
}
__global__ void __launch_bounds__(256)
scan_p3(int* __restrict__ rp, const int* __restrict__ bsum, int* __restrict__ cursor,
        int n, int e) {
  int i = blockIdx.x * 256 + threadIdx.x;
  if (i < n) {
    int v = rp[i] + bsum[blockIdx.x];
    rp[i] = v;
    cursor[i] = v;
  }
  if (i == 0) rp[n] = e;
}
__global__ void scatter_edges_kernel(const int* __restrict__ src, const int* __restrict__ dst,
                                     int* __restrict__ cursor, int* __restrict__ ssrc,
                                     int* __restrict__ sdst, int e) {
  int i = blockIdx.x * 256 + threadIdx.x;
  if (i < e) {
    int d = dst[i];
    int pos = atomicAdd(&cursor[d], 1);
    ssrc[pos] = src[i];
    sdst[pos] = d;
  }
}

// ---------------- merged small setup kernels ----------------
DEVINL void bn1(const float* g, const float* b, const float* m, const float* v,
                float* sc, float* sh, int i) {
  float s = g[i] * rsqrtf(v[i] + 1e-5f);
  sc[i] = s;
  sh[i] = b[i] - m[i] * s;
}
__global__ void bn_prep_all(const float* g1, const float* b1, const float* m1, const float* v1,
                            float* sc1, float* sh1, const float* g2, const float* b2,
                            const float* m2, const float* v2, float* sc2, float* sh2,
                            const float* g3, const float* b3, const float* m3, const float* v3,
                            float* sc3, float* sh3) {
  int i = blockIdx.x * 256 + threadIdx.x;  // 1024 total
  if (i < 512) bn1(g1, b1, m1, v1, sc1, sh1, i);
  else if (i < 768) bn1(g2, b2, m2, v2, sc2, sh2, i - 512);
  else if (i < 1024) bn1(g3, b3, m3, v3, sc3, sh3, i - 768);
}

// W pre-transform into frag image (split bf16 hi/lo).  Per 32-k chunk (16 KB):
// hi 8 KB then lo 8 KB; frag = (ct*4+kq)*16+n (ct=c>>4, kq=(k>>3)&3, n=c&15), j=k&7.
DEVINL void wfrag1(const float* W, unsigned short* out, int e) {
  int k = e >> 7, c = e & 127;
  unsigned short h, l;
  split_bf16(W[e], h, l);
  int chunk = k >> 5, kq = (k >> 3) & 3, j = k & 7, ct = c >> 4, n = c & 15;
  int frag = (ct * 4 + kq) * 16 + n;
  size_t o = (size_t)chunk * 8192 + frag * 8 + j;
  out[o] = h;
  out[o + 4096] = l;
}
__global__ void wfrag_all(const float* __restrict__ e1W, const float* __restrict__ e2W,
                          const float* __restrict__ e3W, unsigned short* b1p,
                          unsigned short* b1q, unsigned short* b2p, unsigned short* b2q,
                          unsigned short* b3p, unsigned short* b3q) {
  int g = blockIdx.x * 256 + threadIdx.x;  // 131072 total
  if (g < 32768) wfrag1(e1W, b1p, g);
  else if (g < 65536) wfrag1(e1W + 32768, b1q, g - 32768);
  else if (g < 81920) wfrag1(e2W, b2p, g - 65536);
  else if (g < 98304) wfrag1(e2W + 16384, b2q, g - 81920);
  else if (g < 114688) wfrag1(e3W, b3p, g - 98304);
  else wfrag1(e3W + 16384, b3q, g - 114688);
}

// combine: H = Q written ? P + dec(Q) : 0 ; optionally re-zero Q for next layer
__global__ void combine_kernel(unsigned* __restrict__ Q, const float* __restrict__ P,
                               float* __restrict__ H, int n, int zq) {
  int i = blockIdx.x * 256 + threadIdx.x;
  if (i < n) {
    unsigned e = Q[i];
    H[i] = e ? (P[i] + dec_f32(e)) : 0.f;
    if (zq) Q[i] = 0u;
  }
}

// ---------------- input projection: rows 0 mod 4 use Wm/bm, else Wc/bc ----------------
// writes Y0 = (x@W + b) * dinv[row]  (pre-scaled for the aggregate)
__global__ void __launch_bounds__(256)
proj_kernel(const float* __restrict__ X, const float* __restrict__ Wm,
            const float* __restrict__ bm, const float* __restrict__ Wc,
            const float* __restrict__ bc, const float* __restrict__ dinv,
            float* __restrict__ Y0) {
  __shared__ float xs[16][IN_FEATS];  // 32 KB
  int tid = threadIdx.x;
  int rowBase = blockIdx.x * 16;
  for (int i = 0; i < 8; ++i) {
    int idx = i * 256 + tid;
    int r = idx >> 7, kq = idx & 127;
    *reinterpret_cast<float4*>(&xs[r][kq * 4]) =
        *reinterpret_cast<const float4*>(X + (size_t)(rowBase + r) * IN_FEATS + kq * 4);
  }
  __syncthreads();
  int r4 = tid >> 6;  // residue class (wave-uniform); wave0 -> Wm, else Wc
  int j = tid & 63;
  const float* W = (r4 == 0) ? Wm : Wc;
  float a0 = 0.f, a1 = 0.f, a2 = 0.f, a3 = 0.f;
#pragma unroll 4
  for (int k = 0; k < IN_FEATS; ++k) {
    float w = W[k * 64 + j];
    a0 = fmaf(xs[r4][k], w, a0);
    a1 = fmaf(xs[r4 + 4][k], w, a1);
    a2 = fmaf(xs[r4 + 8][k], w, a2);
    a3 = fmaf(xs[r4 + 12][k], w, a3);
  }
  float b = (r4 == 0) ? bm[j] : bc[j];
  int r0 = rowBase + r4;
  Y0[(size_t)r0 * 64 + j] = (a0 + b) * dinv[r0];
  Y0[(size_t)(r0 + 4) * 64 + j] = (a1 + b) * dinv[r0 + 4];
  Y0[(size_t)(r0 + 8) * 64 + j] = (a2 + b) * dinv[r0 + 8];
  Y0[(size_t)(r0 + 12) * 64 + j] = (a3 + b) * dinv[r0 + 12];
}

// ------- GCN aggregate (CSR gather, float4): Z_d = dinv_d * (Y_d + sum Y_src) -------
template <int LOGF4>
__global__ void __launch_bounds__(256)
agg_kernel(const float* __restrict__ Y, const int* __restrict__ row_ptr,
           const int* __restrict__ ssrc, const float* __restrict__ dinv,
           float* __restrict__ Z, int n) {
  constexpr int F4 = 1 << LOGF4;
  int g = blockIdx.x * 256 + threadIdx.x;
  int d = g >> LOGF4, c4 = g & (F4 - 1);
  if (d >= n) return;
  const float4* Yp = (const float4*)Y;
  float4 a = Yp[(size_t)d * F4 + c4];  // self term (Y already *dinv)
  float ax = a.x, ay = a.y, az = a.z, aw = a.w;
  int e = row_ptr[d], end = row_ptr[d + 1];
  for (; e + 3 < end; e += 4) {  // 4 independent loads in flight
    int s0 = ssrc[e], s1 = ssrc[e + 1], s2 = ssrc[e + 2], s3 = ssrc[e + 3];
    float4 v0 = Yp[(size_t)s0 * F4 + c4];
    float4 v1 = Yp[(size_t)s1 * F4 + c4];
    float4 v2 = Yp[(size_t)s2 * F4 + c4];
    float4 v3 = Yp[(size_t)s3 * F4 + c4];
    ax += (v0.x + v1.x) + (v2.x + v3.x);
    ay += (v0.y + v1.y) + (v2.y + v3.y);
    az += (v0.z + v1.z) + (v2.z + v3.z);
    aw += (v0.w + v1.w) + (v2.w + v3.w);
  }
  for (; e < end; ++e) {
    float4 v = Yp[(size_t)ssrc[e] * F4 + c4];
    ax += v.x; ay += v.y; az += v.z; aw += v.w;
  }
  float s = dinv[d];
  ((float4*)Z)[(size_t)d * F4 + c4] = make_float4(ax * s, ay * s, az * s, aw * s);
}

// ------- GCN dense: H = Z@W + b  (optionally * dinv[row] for the next aggregate) -------
template <int K, int F, bool SCALE>
__global__ void __launch_bounds__(256)
gemm_kernel(const float* __restrict__ X, const float* __restrict__ W,
            const float* __restrict__ bias, const float* __restrict__ dinv,
            float* __restrict__ H, int n) {
  __shared__ float Xs[64][K + 1];
  __shared__ float Ws[K][65];
  int tid = threadIdx.x;
  int rowBase = blockIdx.x * 64;
  int colBase = blockIdx.y * 64;
  for (int idx = tid; idx < 64 * K; idx += 256) {
    int r = idx / K, k = idx % K;
    int row = rowBase + r;
    Xs[r][k] = (row < n) ? X[(size_t)row * K + k] : 0.f;
  }
  for (int idx = tid; idx < K * 64; idx += 256) {
    int k = idx >> 6, c = idx & 63;
    Ws[k][c] = W[(size_t)k * F + colBase + c];
  }
  __syncthreads();
  int tx = tid & 15, ty = tid >> 4;
  float acc[4][4] = {};
  for (int k = 0; k < K; ++k) {
    float a[4], b[4];
#pragma unroll
    for (int r = 0; r < 4; ++r) a[r] = Xs[ty * 4 + r][k];
#pragma unroll
    for (int c = 0; c < 4; ++c) b[c] = Ws[k][tx * 4 + c];
#pragma unroll
    for (int r = 0; r < 4; ++r)
#pragma unroll
      for (int c = 0; c < 4; ++c) acc[r][c] = fmaf(a[r], b[c], acc[r][c]);
  }
#pragma unroll
  for (int r = 0; r < 4; ++r) {
    int row = rowBase + ty * 4 + r;
    if (row < n) {
      float di = SCALE ? dinv[row] : 1.0f;
#pragma unroll
      for (int c = 0; c < 4; ++c) {
        int col = colBase + tx * 4 + c;
        float v = acc[r][c] + bias[col];
        H[(size_t)row * F + col] = SCALE ? v * di : v;
      }
    }
  }
}

// ---------------- EdgeConv split-bf16 MFMA GEMM, v6 (barrier-free K-loop) ----------------
// 128 rows x 128 cols per block, 4 waves; wave w owns rows [w*32, w*32+32).
// ALL of B (4 chunks, hi+lo = 64 KB) is staged into LDS once (C=256: two halves,
// 3 barriers total).  The K-loop has NO barriers: each wave free-runs its
// gather -> split -> ds_read -> MFMA pipeline, so co-resident waves interleave
// VALU/MFMA/LDS phases instead of lockstepping on a per-chunk __syncthreads
// (round-5 lockstep left every pipe <25% busy).
DEVINL void proc8(const float4& va, const float4& vb, const float4& sa, const float4& sb,
                  const float4& ha, const float4& hb, short8& hi, short8& lo) {
  float f[8] = {va.x, va.y, va.z, va.w, vb.x, vb.y, vb.z, vb.w};
  float s[8] = {sa.x, sa.y, sa.z, sa.w, sb.x, sb.y, sb.z, sb.w};
  float t[8] = {ha.x, ha.y, ha.z, ha.w, hb.x, hb.y, hb.z, hb.w};
#pragma unroll
  for (int j = 0; j < 8; ++j) {
    float v = fmaxf(fmaf(f[j], s[j], t[j]), 0.f);
    unsigned short hh, ll;
    split_bf16(v, hh, ll);
    hi[j] = (short)hh;
    lo[j] = (short)ll;
  }
}

template <int C, bool EDGE>
__global__ void __launch_bounds__(256, 2)
ec_mfma_kernel(const float* __restrict__ X, const int* __restrict__ ssrc,
               const int* __restrict__ sdst, const float* __restrict__ scale,
               const float* __restrict__ shift, const unsigned short* __restrict__ Bfrag,
               unsigned* __restrict__ outU, float* __restrict__ outP, int nrows) {
  constexpr int NCH = C / 32;
  constexpr int HALVES = C / 128;
  __shared__ unsigned short Bmat[32768];  // 64 KB: 4 chunks x (hi 8KB + lo 8KB)
  __shared__ int de_s[128];
  const int tid = threadIdx.x, lane = tid & 63, wv = tid >> 6;
  const int q = lane >> 4, mn = lane & 15;
  const int base = blockIdx.x * 128;
  const int koff = q * 8;
  const int lr0 = wv * 32 + mn, lr1 = lr0 + 16;  // local rows this lane loads A for

  int id0, id1, is0 = 0, is1 = 0;
  if (EDGE) {
    if (tid < 128) de_s[tid] = sdst[base + tid];
    is0 = ssrc[base + lr0];
    id0 = sdst[base + lr0];
    is1 = ssrc[base + lr1];
    id1 = sdst[base + lr1];
  } else {
    id0 = min(base + lr0, nrows - 1);
    id1 = min(base + lr1, nrows - 1);
  }
  const float* pd0 = X + (size_t)id0 * C + koff;
  const float* pd1 = X + (size_t)id1 * C + koff;
  const float* ps0 = EDGE ? X + (size_t)is0 * C + koff : nullptr;
  const float* ps1 = EDGE ? X + (size_t)is1 * C + koff : nullptr;

  f32x4 acc[8][2];
#pragma unroll
  for (int i = 0; i < 8; ++i) {
    acc[i][0] = (f32x4)0.f;
    acc[i][1] = (f32x4)0.f;
  }

  // prologue: A(0) into regs, then stage B half 0 (64 KB, 16 glds16 per wave)
  float4 pa0, pa1, pa2, pa3, pb0, pb1, pb2, pb3;
  pa0 = *(const float4*)(pd0);
  pa1 = *(const float4*)(pd0 + 4);
  pa2 = *(const float4*)(pd1);
  pa3 = *(const float4*)(pd1 + 4);
  if (EDGE) {
    pb0 = *(const float4*)(ps0);
    pb1 = *(const float4*)(ps0 + 4);
    pb2 = *(const float4*)(ps1);
    pb3 = *(const float4*)(ps1 + 4);
  }
  {
    const unsigned short* bs = Bfrag + lane * 8;
#pragma unroll
    for (int i = 0; i < 16; ++i) {
      int seg = wv * 16 + i;
      glds16(bs + seg * 512, Bmat + seg * 512);
    }
  }
  __syncthreads();  // B half 0 resident (drains DMA + A(0) loads)

  for (int h = 0; h < HALVES; ++h) {
    if (h > 0) {
      __syncthreads();  // all waves done reading previous half of Bmat
      const unsigned short* bs = Bfrag + 32768 + lane * 8;
#pragma unroll
      for (int i = 0; i < 16; ++i) {
        int seg = wv * 16 + i;
        glds16(bs + seg * 512, Bmat + seg * 512);
      }
      __syncthreads();
    }
#pragma unroll
    for (int cc = 0; cc < 4; ++cc) {
      const int c = h * 4 + cc;
      const int kc = c * 32;
      float4 sca = *(const float4*)(scale + kc + koff);
      float4 scb = *(const float4*)(scale + kc + koff + 4);
      float4 sha = *(const float4*)(shift + kc + koff);
      float4 shb = *(const float4*)(shift + kc + koff + 4);
      float4 u0, u1, u2, u3;
      if (EDGE) {
        u0 = make_float4(pb0.x - pa0.x, pb0.y - pa0.y, pb0.z - pa0.z, pb0.w - pa0.w);
        u1 = make_float4(pb1.x - pa1.x, pb1.y - pa1.y, pb1.z - pa1.z, pb1.w - pa1.w);
        u2 = make_float4(pb2.x - pa2.x, pb2.y - pa2.y, pb2.z - pa2.z, pb2.w - pa2.w);
        u3 = make_float4(pb3.x - pa3.x, pb3.y - pa3.y, pb3.z - pa3.z, pb3.w - pa3.w);
      } else {
        u0 = pa0; u1 = pa1; u2 = pa2; u3 = pa3;
      }
      short8 ah0, al0, ah1, al1;
      proc8(u0, u1, sca, scb, sha, shb, ah0, al0);
      proc8(u2, u3, sca, scb, sha, shb, ah1, al1);
      if (c + 1 < NCH) {  // prefetch A(c+1); consumed next iteration (or next half)
        const int k2 = kc + 32;
        pa0 = *(const float4*)(pd0 + k2);
        pa1 = *(const float4*)(pd0 + k2 + 4);
        pa2 = *(const float4*)(pd1 + k2);
        pa3 = *(const float4*)(pd1 + k2 + 4);
        if (EDGE) {
          pb0 = *(const float4*)(ps0 + k2);
          pb1 = *(const float4*)(ps0 + k2 + 4);
          pb2 = *(const float4*)(ps1 + k2);
          pb3 = *(const float4*)(ps1 + k2 + 4);
        }
      }
      const unsigned short* Bc = Bmat + cc * 8192;
#pragma unroll
      for (int ct = 0; ct < 8; ++ct) {
        int fi = ct * 64 + lane;
        short8 bh = *(const short8*)(Bc + fi * 8);
        short8 bl = *(const short8*)(Bc + 4096 + fi * 8);
        acc[ct][0] = __builtin_amdgcn_mfma_f32_16x16x32_bf16(ah0, bh, acc[ct][0], 0, 0, 0);
        acc[ct][1] = __builtin_amdgcn_mfma_f32_16x16x32_bf16(ah1, bh, acc[ct][1], 0, 0, 0);
        acc[ct][0] = __builtin_amdgcn_mfma_f32_16x16x32_bf16(ah0, bl, acc[ct][0], 0, 0, 0);
        acc[ct][1] = __builtin_amdgcn_mfma_f32_16x16x32_bf16(ah1, bl, acc[ct][1], 0, 0, 0);
        acc[ct][0] = __builtin_amdgcn_mfma_f32_16x16x32_bf16(al0, bh, acc[ct][0], 0, 0, 0);
        acc[ct][1] = __builtin_amdgcn_mfma_f32_16x16x32_bf16(al1, bh, acc[ct][1], 0, 0, 0);
      }
    }
  }

  // ---- epilogue: C/D layout col=lane&15, row=q*4+reg; rows dst-sorted -> run-merge ----
  if (EDGE) {
#pragma unroll
    for (int ct = 0; ct < 8; ++ct) {
      int f = ct * 16 + mn;
      float mv = 0.f;
      int prev = -1;
#pragma unroll
      for (int g = 0; g < 2; ++g) {
        int e0 = wv * 32 + g * 16 + q * 4;
#pragma unroll
        for (int r = 0; r < 4; ++r) {
          int d = de_s[e0 + r];
          float v = acc[ct][g][r];
          if (prev < 0) {
            prev = d; mv = v;
          } else if (d == prev) {
            mv = fmaxf(mv, v);
          } else {
            atomicMax(&outU[(size_t)prev * 128 + f], enc_f32(mv));
            prev = d; mv = v;
          }
        }
      }
      atomicMax(&outU[(size_t)prev * 128 + f], enc_f32(mv));
    }
  } else {
#pragma unroll
    for (int ct = 0; ct < 8; ++ct) {
      int f = ct * 16 + mn;
#pragma unroll
      for (int g = 0; g < 2; ++g) {
        int r0 = base + wv * 32 + g * 16 + q * 4;
#pragma unroll
        for (int r = 0; r < 4; ++r) {
          int row = r0 + r;
          if (row < nrows) outP[(size_t)row * 128 + f] = acc[ct][g][r];
        }
      }
    }
  }
}

// ---------------- final FC: out[i] = h[i,0:128] . Wfc + bfc ----------------
__global__ void __launch_bounds__(256)
fc_kernel(const float* __restrict__ Hf, const float* __restrict__ Wfc,
          const float* __restrict__ bfc, float* __restrict__ out, int n) {
  int g = blockIdx.x * 256 + threadIdx.x;
  int node = g >> 6, lane = g & 63;
  if (node >= n) return;
  float v = fmaf(Hf[(size_t)node * 128 + lane], Wfc[lane],
                 Hf[(size_t)node * 128 + 64 + lane] * Wfc[64 + lane]);
#pragma unroll
  for (int off = 32; off > 0; off >>= 1) v += __shfl_down(v, off);
  if (lane == 0) out[node] = v + bfc[0];
}

extern "C" void kernel_launch(void* const* d_in, const int* in_sizes, int n_in,
                              void* d_out, int out_size, void* d_ws, size_t ws_size,
                              hipStream_t stream) {
  const float* x   = (const float*)d_in[0];
  const int*   ei  = (const int*)d_in[1];
  const float* Wm  = (const float*)d_in[2];
  const float* bm  = (const float*)d_in[3];
  const float* Wc  = (const float*)d_in[4];
  const float* bc  = (const float*)d_in[5];
  const float* Wg1 = (const float*)d_in[6];
  const float* bg1 = (const float*)d_in[7];
  const float* Wg2 = (const float*)d_in[8];
  const float* bg2 = (const float*)d_in[9];
  const float* Wg3 = (const float*)d_in[10];
  const float* bg3 = (const float*)d_in[11];
  const float* e1g = (const float*)d_in[12];
  const float* e1b = (const float*)d_in[13];
  const float* e1m = (const float*)d_in[14];
  const float* e1v = (const float*)d_in[15];
  const float* e1W = (const float*)d_in[16];
  const float* e2g = (const float*)d_in[17];
  const float* e2b = (const float*)d_in[18];
  const float* e2m = (const float*)d_in[19];
  const float* e2v = (const float*)d_in[20];
  const float* e2W = (const float*)d_in[21];
  const float* e3g = (const float*)d_in[22];
  const float* e3b = (const float*)d_in[23];
  const float* e3m = (const float*)d_in[24];
  const float* e3v = (const float*)d_in[25];
  const float* e3W = (const float*)d_in[26];
  const float* Wfc = (const float*)d_in[27];
  const float* bfc = (const float*)d_in[28];

  const int* src = ei;
  const int* dst = ei + N_EDGES;

  // ---- workspace layout (floats), ~50 MB ----
  float* ws   = (float*)d_ws;
  float* dinv = ws;                                   // N
  float* y0   = dinv + N_NODES;                       // N*64
  float* zb   = y0 + (size_t)N_NODES * 64;            // N*128 (Z, later P)
  float* yb   = zb + (size_t)N_NODES * 128;           // N*128 (Y1/Y2, later Q)
  float* G    = yb + (size_t)N_NODES * 128;           // N*256 (G; H1@base, H2@+N*128, H3@base)
  float* sc1  = G + (size_t)N_NODES * 256;            // 512
  float* sh1  = sc1 + 512;
  float* sc2  = sh1 + 512;                            // 256
  float* sh2  = sc2 + 256;
  float* sc3  = sh2 + 256;
  float* sh3  = sc3 + 256;
  unsigned short* bf1p = (unsigned short*)(sh3 + 256);  // frag images, 512 KB total
  unsigned short* bf1q = bf1p + 65536;
  unsigned short* bf2p = bf1q + 65536;
  unsigned short* bf2q = bf2p + 32768;
  unsigned short* bf3p = bf2q + 32768;
  unsigned short* bf3q = bf3p + 32768;
  int* cnt     = (int*)(bf3q + 32768);                // N
  int* row_ptr = cnt + N_NODES;                       // N+1
  int* cursor  = row_ptr + N_NODES + 1;               // N
  int* bsum    = cursor + N_NODES;                    // 256
  int* ssrc    = bsum + 256;                          // E
  int* sdst    = ssrc + N_EDGES;                      // E

  float*    Pbuf = zb;
  unsigned* Qbuf = (unsigned*)yb;

  // ---- CSR build (counting sort by dst) + dinv ----
  hipMemsetAsync(cnt, 0, N_NODES * sizeof(int), stream);
  hist_kernel<<<N_EDGES / 256, 256, 0, stream>>>(dst, cnt, N_EDGES);
  dinv_kernel<<<79, 256, 0, stream>>>(cnt, dinv, N_NODES);
  scan_p1<<<79, 256, 0, stream>>>(cnt, row_ptr, bsum, N_NODES);
  scan_p2<<<1, 256, 0, stream>>>(bsum, 79);
  scan_p3<<<79, 256, 0, stream>>>(row_ptr, bsum, cursor, N_NODES, N_EDGES);
  scatter_edges_kernel<<<N_EDGES / 256, 256, 0, stream>>>(src, dst, cursor, ssrc, sdst,
                                                          N_EDGES);

  // ---- BN fold + W frag pre-transforms (merged) ----
  bn_prep_all<<<4, 256, 0, stream>>>(e1g, e1b, e1m, e1v, sc1, sh1, e2g, e2b, e2m, e2v, sc2,
                                     sh2, e3g, e3b, e3m, e3v, sc3, sh3);
  wfrag_all<<<512, 256, 0, stream>>>(e1W, e2W, e3W, bf1p, bf1q, bf2p, bf2q, bf3p, bf3q);

  // ---- GCN: aggregate-first reassociation  H = (A~ X) W + b ----
  proj_kernel<<<N_NODES / 16, 256, 0, stream>>>(x, Wm, bm, Wc, bc, dinv, y0);
  dim3 grid2(313, 2), grid4(313, 4);
  agg_kernel<4><<<N_NODES * 16 / 256, 256, 0, stream>>>(y0, row_ptr, ssrc, dinv, zb, N_NODES);
  gemm_kernel<64, 128, true><<<grid2, 256, 0, stream>>>(zb, Wg1, bg1, dinv, yb, N_NODES);
  agg_kernel<5><<<N_NODES * 32 / 256, 256, 0, stream>>>(yb, row_ptr, ssrc, dinv, zb, N_NODES);
  gemm_kernel<128, 128, true><<<grid2, 256, 0, stream>>>(zb, Wg2, bg2, dinv, yb, N_NODES);
  agg_kernel<5><<<N_NODES * 32 / 256, 256, 0, stream>>>(yb, row_ptr, ssrc, dinv, zb, N_NODES);
  gemm_kernel<128, 256, false><<<grid4, 256, 0, stream>>>(zb, Wg3, bg3, dinv, G, N_NODES);

  const int NODE_BLOCKS = (N_NODES + 127) / 128;  // 157
  const int EDGE_BLOCKS = N_EDGES / 128;          // 2500
  const int NB_ELEM     = N_NODES * 128 / 256;    // 10000

  float* H1 = G;                        // combine1 -> G base (G dead after EC1)
  float* H2 = G + (size_t)N_NODES * 128;
  float* H3 = G;

  // EdgeConv 1: G [N,256] -> H1 [N,128]
  hipMemsetAsync(Qbuf, 0, (size_t)N_NODES * 128 * 4, stream);
  ec_mfma_kernel<256, false><<<NODE_BLOCKS, 256, 0, stream>>>(
      G, nullptr, nullptr, sc1, sh1, bf1p, nullptr, Pbuf, N_NODES);
  ec_mfma_kernel<256, true><<<EDGE_BLOCKS, 256, 0, stream>>>(
      G, ssrc, sdst, sc1 + 256, sh1 + 256, bf1q, Qbuf, nullptr, N_NODES);
  combine_kernel<<<NB_ELEM, 256, 0, stream>>>(Qbuf, Pbuf, H1, N_NODES * 128, 1);

  // EdgeConv 2: H1 -> H2
  ec_mfma_kernel<128, false><<<NODE_BLOCKS, 256, 0, stream>>>(
      H1, nullptr, nullptr, sc2, sh2, bf2p, nullptr, Pbuf, N_NODES);
  ec_mfma_kernel<128, true><<<EDGE_BLOCKS, 256, 0, stream>>>(
      H1, ssrc, sdst, sc2 + 128, sh2 + 128, bf2q, Qbuf, nullptr, N_NODES);
  combine_kernel<<<NB_ELEM, 256, 0, stream>>>(Qbuf, Pbuf, H2, N_NODES * 128, 1);

  // EdgeConv 3: H2 -> H3 (over H1, dead)
  ec_mfma_kernel<128, false><<<NODE_BLOCKS, 256, 0, stream>>>(
      H2, nullptr, nullptr, sc3, sh3, bf3p, nullptr, Pbuf, N_NODES);
  ec_mfma_kernel<128, true><<<EDGE_BLOCKS, 256, 0, stream>>>(
      H2, ssrc, sdst, sc3 + 128, sh3 + 128, bf3q, Qbuf, nullptr, N_NODES);
  combine_kernel<<<NB_ELEM, 256, 0, stream>>>(Qbuf, Pbuf, H3, N_NODES * 128, 0);

  // final FC
  fc_kernel<<<N_NODES * 64 / 256, 256, 0, stream>>>(H3, Wfc, bfc, (float*)d_out, N_NODES);
}